// Round 9
// baseline (239.601 us; speedup 1.0000x reference)
//
#include <hip/hip_runtime.h>
#include <hip/hip_bf16.h>

#define P_BOX 512
#define NP    50000
#define NPAD  50176
#define KM    64
#define NKEY  4096
#define HF    160
#define WF    512

typedef unsigned long long u64;
typedef unsigned short u16;
typedef unsigned int u32;
typedef __attribute__((ext_vector_type(8))) short short8;
typedef __attribute__((ext_vector_type(4))) float f32x4;

__device__ __forceinline__ u16 f2bf(float f) {
  u32 u = __float_as_uint(f);
  u32 r = u + 0x7fffu + ((u >> 16) & 1u);
  return (u16)(r >> 16);
}
__device__ __forceinline__ float bf2f(u16 h) { return __uint_as_float(((u32)h) << 16); }
__device__ __forceinline__ float bfl(u32 u) { return __uint_as_float(u << 16); }
__device__ __forceinline__ float bfh(u32 u) { return __uint_as_float(u & 0xffff0000u); }

// A-buffer: 64 rows x 256 bf16, 16B granules XOR-swizzled by row (g' = g ^ (m&7))
__device__ __forceinline__ int aIdx(int m, int d) {
  return m * 256 + (((d >> 3) ^ (m & 7)) << 3) + (d & 7);
}
__device__ __forceinline__ const short8* aGr(const u16* A, int m, int g) {
  return (const short8*)(A + m * 256 + ((g ^ (m & 7)) << 3));
}

// ================= unified prep kernel: 1386 blocks x 256 threads =================
__launch_bounds__(256)
__global__ void k_prep(const float* __restrict__ pts, const float* __restrict__ img,
                       const float* __restrict__ q_w, const float* __restrict__ q_b,
                       const float* __restrict__ f_w, const float* __restrict__ f_b,
                       const float* __restrict__ o_w1, const float* __restrict__ pe_w1,
                       const float* __restrict__ pe_w2, const float* __restrict__ o_w2,
                       const float* __restrict__ off_w, const float* __restrict__ wt_w,
                       const float* __restrict__ off_b, const float* __restrict__ wt_b,
                       float* __restrict__ xs, float* __restrict__ ys, float* __restrict__ zs,
                       u16* __restrict__ pe_w2T, u16* __restrict__ WqT,
                       u16* __restrict__ o_w2T, u16* __restrict__ FoT,
                       u16* __restrict__ HWT, u16* __restrict__ pe_w1T,
                       float* __restrict__ bq, float* __restrict__ fbo,
                       float* __restrict__ hb, u16* __restrict__ imgT) {
  __shared__ float shbuf[8580];
  const int blk = blockIdx.x;
  const int t = threadIdx.x;

  if (blk < 1280) {
    int w0 = (blk & 7) * 64;
    int h = blk >> 3;
    int c0 = t >> 6, w = t & 63;
    for (int it = 0; it < 24; ++it) {
      int c = it * 4 + c0;
      shbuf[c * 65 + w] = img[(c * HF + h) * WF + w0 + w];
    }
    __syncthreads();
    for (int it = 0; it < 24; ++it) {
      int idx = it * 256 + t;
      int ww = idx / 96, c = idx % 96;
      imgT[((size_t)(h * WF + w0 + ww)) * 96 + c] = f2bf(shbuf[c * 65 + ww]);
    }
  } else if (blk < 1329) {
    int g = blk - 1280;
#pragma unroll
    for (int r = 0; r < 4; ++r) {
      int i = g * 1024 + r * 256 + t;
      if (i < NPAD) {
        if (i < NP) {
          xs[i] = pts[i * 7 + 0];
          ys[i] = pts[i * 7 + 1];
          zs[i] = pts[i * 7 + 2];
        } else {
          xs[i] = 1e9f; ys[i] = 1e9f; zs[i] = 1e9f;
        }
      }
    }
  } else if (blk < 1353) {
    int gg = blk - 1329;
    const bool isWq = gg < 16;
    const int g = isWq ? gg : gg - 16;
    const int n0 = (g & 3) * 64;
    const int x0 = (g >> 2) * 64;
    float* sA = shbuf;
    float* sB = shbuf + 64 * 65;
    float acc[4][4];
#pragma unroll
    for (int r = 0; r < 4; ++r)
#pragma unroll
      for (int c = 0; c < 4; ++c) acc[r][c] = 0.f;
    const int tx = t & 15, ty = t >> 4;
    for (int j0 = 0; j0 < 256; j0 += 64) {
      {
        int nn = t & 63, jb = t >> 6;
#pragma unroll
        for (int r = 0; r < 16; ++r) {
          int jj = jb + r * 4;
          int row = (isWq ? 0 : 256) + j0 + jj;
          sA[jj * 65 + nn] = o_w1[row * 256 + n0 + nn];
        }
      }
      {
        int jj = t & 63, xb = t >> 6;
#pragma unroll
        for (int r = 0; r < 16; ++r) {
          int xx = xb + r * 4;
          float v = 0.f;
          if (isWq) v = q_w[(x0 + xx) * 256 + j0 + jj];
          else if (x0 + xx < 96) v = f_w[(x0 + xx) * 256 + j0 + jj];
          sB[jj * 65 + xx] = v;
        }
      }
      __syncthreads();
#pragma unroll 8
      for (int jj = 0; jj < 64; ++jj) {
        float a[4], b[4];
#pragma unroll
        for (int r = 0; r < 4; ++r) a[r] = sA[jj * 65 + ty * 4 + r];
#pragma unroll
        for (int c = 0; c < 4; ++c) b[c] = sB[jj * 65 + tx * 4 + c];
#pragma unroll
        for (int r = 0; r < 4; ++r)
#pragma unroll
          for (int c = 0; c < 4; ++c) acc[r][c] += a[r] * b[c];
      }
      __syncthreads();
    }
    if (isWq) {
#pragma unroll
      for (int r = 0; r < 4; ++r) {
        ushort4 o;
        o.x = f2bf(acc[r][0]); o.y = f2bf(acc[r][1]);
        o.z = f2bf(acc[r][2]); o.w = f2bf(acc[r][3]);
        *(ushort4*)(WqT + (size_t)(n0 + ty * 4 + r) * 256 + x0 + tx * 4) = o;
      }
    } else if (x0 + tx * 4 < 96) {
#pragma unroll
      for (int r = 0; r < 4; ++r) {
        ushort4 o;
        o.x = f2bf(acc[r][0]); o.y = f2bf(acc[r][1]);
        o.z = f2bf(acc[r][2]); o.w = f2bf(acc[r][3]);
        *(ushort4*)(FoT + (size_t)(n0 + ty * 4 + r) * 96 + x0 + tx * 4) = o;
      }
    }
  } else if (blk < 1385) {
    int g = blk - 1353;
    const float* src = (g < 16) ? pe_w2 : o_w2;
    u16* dst = (g < 16) ? pe_w2T : o_w2T;
    int tile = g & 15;
    int n0 = (tile & 3) * 64, k0 = (tile >> 2) * 64;
    {
      int nn = t & 63, kb = t >> 6;
#pragma unroll
      for (int r = 0; r < 16; ++r) {
        int kk = kb + r * 4;
        shbuf[kk * 65 + nn] = src[(k0 + kk) * 256 + n0 + nn];
      }
    }
    __syncthreads();
    {
      int kk = t & 63, nb = t >> 6;
#pragma unroll
      for (int r = 0; r < 16; ++r) {
        int nn = nb + r * 4;
        dst[(size_t)(n0 + nn) * 256 + k0 + kk] = f2bf(shbuf[kk * 65 + nn]);
      }
    }
  } else {
    int n = t;
    float a1 = 0.f, a2 = 0.f;
    for (int j = 0; j < 256; ++j) {
      a1 += q_b[j] * o_w1[j * 256 + n];
      a2 += f_b[j] * o_w1[(256 + j) * 256 + n];
    }
    bq[n] = a1;
    fbo[n] = a2;
#pragma unroll
    for (int s = 0; s < 16; ++s) {
      float v = (s < 8) ? off_w[n * 8 + s] : ((s < 12) ? wt_w[n * 4 + (s - 8)] : 0.f);
      HWT[s * 256 + n] = f2bf(v);
    }
#pragma unroll
    for (int k = 0; k < 32; ++k)
      pe_w1T[n * 32 + k] = (k < 8) ? f2bf(pe_w1[k * 256 + n]) : (u16)0;
    if (t < 16) hb[t] = (t < 8) ? off_b[t] : ((t < 12) ? wt_b[t - 8] : 0.f);
  }
}

// ================ selection kernel: phases 1-3b, NO MFMA =================
// Zero AGPR reservation; demand ~30 arch regs -> spill-free. LDS ~45 KB ->
// 3 blocks/CU for the latency-bound 50K-point scan.
// Outputs per box: TOK (64 x uint4 packed bf16 token row), VM, REF, CNT, counts.
__launch_bounds__(512)
__global__ void k_sel(const float* __restrict__ pts, const float* __restrict__ boxes,
                      const float* __restrict__ proj,
                      const float* __restrict__ xs, const float* __restrict__ ys,
                      const float* __restrict__ zs,
                      uint4* __restrict__ TOK, float* __restrict__ VM,
                      float* __restrict__ REF, int* __restrict__ CNT,
                      float* __restrict__ out) {
  __shared__ u64 keys[NKEY];     // 32 KB
  __shared__ u64 keys2[KM];
  __shared__ float s_nl[KM * 3], s_ft[KM * 4];
  __shared__ float s_knn[KM * 32];  // 8 KB
  __shared__ int cntp;

  const int p = blockIdx.x;
  const int tid = threadIdx.x;

  const float cx = boxes[p * 7 + 0], cy = boxes[p * 7 + 1], cz = boxes[p * 7 + 2];
  const float dx = boxes[p * 7 + 3], dy = boxes[p * 7 + 4], dz = boxes[p * 7 + 5];
  const float yaw = boxes[p * 7 + 6];
  const float cth = cosf(yaw), sth = sinf(yaw);
  const float hx = dx * 0.5f, hy = dy * 0.5f, hz = dz * 0.5f;
  const float ddx = fmaxf(dx, 1e-3f), ddy = fmaxf(dy, 1e-3f), ddz = fmaxf(dz, 1e-3f);

  if (tid == 0) cntp = 0;
  __syncthreads();

  // ---- phase 1: inside test + candidate append
  for (int i = tid * 4; i < NPAD; i += 2048) {
    float4 x4 = *(const float4*)(xs + i);
    float4 y4 = *(const float4*)(ys + i);
    float4 z4 = *(const float4*)(zs + i);
#pragma unroll
    for (int c = 0; c < 4; ++c) {
      float xv = (c == 0) ? x4.x : (c == 1) ? x4.y : (c == 2) ? x4.z : x4.w;
      float yv = (c == 0) ? y4.x : (c == 1) ? y4.y : (c == 2) ? y4.z : y4.w;
      float zv = (c == 0) ? z4.x : (c == 1) ? z4.y : (c == 2) ? z4.z : z4.w;
      float rx0 = xv - cx, ry0 = yv - cy, rz0 = zv - cz;
      float lx = rx0 * cth + ry0 * sth;
      float ly = ry0 * cth - rx0 * sth;
      if (fabsf(lx) <= hx && fabsf(ly) <= hy && fabsf(rz0) <= hz) {
        int pos = atomicAdd(&cntp, 1);
        if (pos < NKEY) {
          float nx = lx / ddx, ny = ly / ddy;
          float pl = sqrtf(nx * nx + ny * ny);
          keys[pos] = (((u64)__float_as_uint(pl)) << 32) | (u32)(i + c);
        }
      }
    }
  }
  __syncthreads();
  const int cnt = cntp;
  const int m = min(cnt, KM);

  // ---- phase 2: top-64 selection into keys2
  if (cnt <= KM) {
    if (tid < cnt) keys2[tid] = keys[tid];
  } else {
    int cc = min(cnt, NKEY);
    if (cc <= 1024) {
      u64 k0v = ~0ull, k1v = ~0ull;
      bool h0 = tid < cc, h1 = tid + 512 < cc;
      if (h0) k0v = keys[tid];
      if (h1) k1v = keys[tid + 512];
      int r0 = 0, r1 = 0;
      for (int i = 0; i < cc; ++i) {
        u64 ki = keys[i];
        r0 += (ki < k0v) ? 1 : 0;
        r1 += (ki < k1v) ? 1 : 0;
      }
      if (h0 && r0 < KM) keys2[r0] = k0v;
      if (h1 && r1 < KM) keys2[r1] = k1v;
    } else {
      int nn = 2048;
      while (nn < cc) nn <<= 1;
      for (int i = cc + tid; i < nn; i += 512) keys[i] = ~0ull;
      __syncthreads();
      for (int k = 2; k <= nn; k <<= 1) {
        for (int j = k >> 1; j > 0; j >>= 1) {
          for (int t = tid; t < nn; t += 512) {
            int ixj = t ^ j;
            if (ixj > t) {
              u64 a = keys[t], b = keys[ixj];
              bool up = ((t & k) == 0);
              if ((a > b) == up) { keys[t] = b; keys[ixj] = a; }
            }
          }
          __syncthreads();
        }
      }
      if (tid < KM) keys2[tid] = keys[tid];
    }
  }
  __syncthreads();

  // ---- phase 3: slot build + projection refs + vm  (writes VM/REF to global)
  if (tid < KM) {
    int k = tid;
    float x = 0.f, y = 0.f, z = 0.f, n0 = 0.f, n1 = 0.f, n2 = 0.f;
    float f0 = 0.f, f1 = 0.f, f2 = 0.f, f3 = 0.f;
    if (k < m) {
      u32 pi = (u32)(keys2[k] & 0xffffffffu);
      const float* pp = pts + (size_t)pi * 7;
      x = pp[0]; y = pp[1]; z = pp[2];
      f0 = pp[3]; f1 = pp[4]; f2 = pp[5]; f3 = pp[6];
      float rx0 = x - cx, ry0 = y - cy, rz0 = z - cz;
      float lx = rx0 * cth + ry0 * sth;
      float ly = ry0 * cth - rx0 * sth;
      n0 = lx / ddx; n1 = ly / ddy; n2 = rz0 / ddz - 0.5f;
    }
    s_nl[k * 3 + 0] = n0; s_nl[k * 3 + 1] = n1; s_nl[k * 3 + 2] = n2;
    s_ft[k * 4 + 0] = f0; s_ft[k * 4 + 1] = f1; s_ft[k * 4 + 2] = f2; s_ft[k * 4 + 3] = f3;
    float h0 = proj[0] * x + proj[1] * y + proj[2] * z + proj[3];
    float h1 = proj[4] * x + proj[5] * y + proj[6] * z + proj[7];
    float dep = proj[8] * x + proj[9] * y + proj[10] * z + proj[11];
    float sd = (fabsf(dep) > 1e-3f) ? dep : 1e-3f;
    float rx = 2.f * (h0 / sd) / 1279.f - 1.f;
    float ry = 2.f * (h1 / sd) / 383.f - 1.f;
    bool v = (dep > 0.1f) && (fabsf(rx) <= 1.f) && (fabsf(ry) <= 1.f) && (k < m);
    VM[p * KM + k] = v ? 1.f : 0.f;
    REF[p * KM * 2 + k * 2 + 0] = rx;
    REF[p * KM * 2 + k * 2 + 1] = ry;
  }
  __syncthreads();

  // ---- phase 3b-i: KNN partials (512 threads: 64 slots x 8 partitions)
  {
    int k = tid & 63, part = tid >> 6;
    float a0 = s_nl[k * 3], a1 = s_nl[k * 3 + 1], a2 = s_nl[k * 3 + 2];
    float b0 = 1e30f, b1 = 1e30f, b2 = 1e30f, b3 = 1e30f;
#pragma unroll
    for (int jj = 0; jj < 8; ++jj) {
      int j = part * 8 + jj;
      if (j < m) {
        float d0 = a0 - s_nl[j * 3], d1 = a1 - s_nl[j * 3 + 1], d2 = a2 - s_nl[j * 3 + 2];
        float dd = sqrtf(d0 * d0 + d1 * d1 + d2 * d2 + 1e-12f);
        if (dd < b3) {
          if (dd < b0)      { b3 = b2; b2 = b1; b1 = b0; b0 = dd; }
          else if (dd < b1) { b3 = b2; b2 = b1; b1 = dd; }
          else if (dd < b2) { b3 = b2; b2 = dd; }
          else              { b3 = dd; }
        }
      }
    }
    float* o = s_knn + k * 32 + part * 4;
    o[0] = b0; o[1] = b1; o[2] = b2; o[3] = b3;
  }
  __syncthreads();

  // ---- phase 3b-ii: merge -> density -> packed bf16 token -> TOK global
  if (tid < KM) {
    int k = tid;
    float dens = 0.f;
    if (k < m) {
      float b0 = 1e30f, b1 = 1e30f, b2 = 1e30f, b3 = 1e30f;
#pragma unroll
      for (int i = 0; i < 32; ++i) {
        float dd = s_knn[k * 32 + i];
        if (dd < b3) {
          if (dd < b0)      { b3 = b2; b2 = b1; b1 = b0; b0 = dd; }
          else if (dd < b1) { b3 = b2; b2 = b1; b1 = dd; }
          else if (dd < b2) { b3 = b2; b2 = dd; }
          else              { b3 = dd; }
        }
      }
      int mm = min(m, 4);
      float nbs = 0.f;
      if (mm > 1) nbs += b1;
      if (mm > 2) nbs += b2;
      if (mm > 3) nbs += b3;
      dens = expf(-nbs / (float)max(mm - 1, 1));
    }
    u32 w0 = (u32)f2bf(s_nl[k * 3 + 0]) | ((u32)f2bf(s_nl[k * 3 + 1]) << 16);
    u32 w1 = (u32)f2bf(s_nl[k * 3 + 2]) | ((u32)f2bf(s_ft[k * 4 + 0]) << 16);
    u32 w2 = (u32)f2bf(s_ft[k * 4 + 1]) | ((u32)f2bf(s_ft[k * 4 + 2]) << 16);
    u32 w3 = (u32)f2bf(s_ft[k * 4 + 3]) | ((u32)f2bf(dens) << 16);
    TOK[p * KM + k] = make_uint4(w0, w1, w2, w3);
  }
  if (tid == 0) {
    CNT[p] = cnt;
    out[(size_t)P_BOX * 256 + p] = (float)cnt;  // counts output
  }
}

// ================ MLP kernel: phases 4a-11, MFMA-heavy =================
// No selection live-state (box scalars, keys, cnt logic) -> arch demand ~50
// regs; MFMA accumulators live in the reserved AGPR half -> target: no spill
// at 2 blocks/CU (128 unified budget, 64 arch + 64 AGPR split).
__attribute__((amdgpu_flat_work_group_size(512, 512), amdgpu_waves_per_eu(4, 4)))
__global__ void k_mlp(const u16* __restrict__ pe_w1T, const float* __restrict__ pe_b1,
                      const float* __restrict__ pe_b2,
                      const float* __restrict__ o_b1, const float* __restrict__ o_b2,
                      const float* __restrict__ score_w, const float* __restrict__ score_b,
                      const u16* __restrict__ pe_w2T, const u16* __restrict__ WqT,
                      const u16* __restrict__ o_w2T, const u16* __restrict__ FoT,
                      const u16* __restrict__ HWT,
                      const float* __restrict__ bqv, const float* __restrict__ fbov,
                      const float* __restrict__ hbv,
                      const u16* __restrict__ imgT,
                      const uint4* __restrict__ TOK, const float* __restrict__ VM,
                      const float* __restrict__ REF, const int* __restrict__ CNT,
                      float* __restrict__ out) {
  __shared__ __align__(16) char smem[81920];
  u16* A1 = (u16*)smem;
  u16* A2 = (u16*)(smem + 32768);
  u16* CTX = (u16*)(smem + 65536);
  float* poolf = (float*)(smem + 65536);
  u16* s_tokb = (u16*)(poolf + 640);   // 64x32 bf16 (4 KB)
  float* s_vm = (float*)(smem + 77824);
  float* s_coef = s_vm + 64;
  float* s_wl = s_coef + 64;           // 256 f
  float* s_ref = s_wl + 256;           // 128 f
  float* s_lg = s_ref + 128;           // 64
  float* s_pw = s_lg + 64;             // 64
  u16* s_offb = (u16*)(s_pw + 64);     // 512 u16

  const int p = blockIdx.x;
  const int tid = threadIdx.x;
  const int m = min(CNT[p], KM);

  // ---- load per-box state from k_sel
  if (tid < KM) {
    int k = tid;
    uint4 tv = TOK[p * KM + k];
    uint4* tb = (uint4*)(s_tokb + k * 32);
    tb[0] = tv;
    tb[1] = make_uint4(0, 0, 0, 0);
    tb[2] = make_uint4(0, 0, 0, 0);
    tb[3] = make_uint4(0, 0, 0, 0);
    s_vm[k] = VM[p * KM + k];
    s_ref[k * 2 + 0] = REF[p * KM * 2 + k * 2 + 0];
    s_ref[k * 2 + 1] = REF[p * KM * 2 + k * 2 + 1];
  }
  __syncthreads();

  const int wv = tid >> 6, lane = tid & 63, q = lane >> 4, ln = lane & 15;
  const int n0g = wv * 32;

  // ---- phase 4a: h1 = relu(tok @ pe_w1 + pe_b1) -> A1 bf16 (MFMA K=32, seq-nt)
#pragma unroll
  for (int nt = 0; nt < 2; ++nt) {
    int n = n0g + nt * 16 + ln;
    f32x4 aH[4];
#pragma unroll
    for (int mt = 0; mt < 4; ++mt) aH[mt] = (f32x4)0.f;
    short8 b = *(const short8*)(pe_w1T + (size_t)n * 32 + q * 8);
#pragma unroll
    for (int mt = 0; mt < 4; ++mt) {
      short8 af = *(const short8*)(s_tokb + (ln + 16 * mt) * 32 + q * 8);
      aH[mt] = __builtin_amdgcn_mfma_f32_16x16x32_bf16(af, b, aH[mt], 0, 0, 0);
    }
    float bias = pe_b1[n];
#pragma unroll
    for (int mt = 0; mt < 4; ++mt)
#pragma unroll
      for (int r = 0; r < 4; ++r)
        A1[aIdx(mt * 16 + q * 4 + r, n)] = f2bf(fmaxf(aH[mt][r] + bias, 0.f));
  }
  __syncthreads();

  // ---- phase 4b: h = h1 @ pe_w2 + pe_b2 -> A2 bf16 (MFMA K=256, seq-nt)
#pragma unroll
  for (int nt = 0; nt < 2; ++nt) {
    int n = n0g + nt * 16 + ln;
    f32x4 acc[4];
#pragma unroll
    for (int mt = 0; mt < 4; ++mt) acc[mt] = (f32x4)0.f;
    const u16* B = pe_w2T + (size_t)n * 256 + q * 8;
#pragma unroll
    for (int ks = 0; ks < 8; ++ks) {
      short8 b = *(const short8*)(B + ks * 32);
#pragma unroll
      for (int mt = 0; mt < 4; ++mt) {
        short8 af = *aGr(A1, ln + 16 * mt, ks * 4 + q);
        acc[mt] = __builtin_amdgcn_mfma_f32_16x16x32_bf16(af, b, acc[mt], 0, 0, 0);
      }
    }
    float bias = pe_b2[n];
#pragma unroll
    for (int mt = 0; mt < 4; ++mt)
#pragma unroll
      for (int r = 0; r < 4; ++r)
        A2[aIdx(mt * 16 + q * 4 + r, n)] = f2bf(acc[mt][r] + bias);
  }
  __syncthreads();

  // ---- phase 5: off/wt heads via one 16-col MFMA (waves 0..3)
  if (wv < 4) {
    f32x4 acc = (f32x4)0.f;
    const u16* B = HWT + (size_t)ln * 256 + q * 8;
#pragma unroll
    for (int ks = 0; ks < 8; ++ks) {
      short8 af = *aGr(A2, ln + 16 * wv, ks * 4 + q);
      short8 b = *(const short8*)(B + ks * 32);
      acc = __builtin_amdgcn_mfma_f32_16x16x32_bf16(af, b, acc, 0, 0, 0);
    }
    float hb_ = hbv[ln];
#pragma unroll
    for (int r = 0; r < 4; ++r) {
      int mm = wv * 16 + q * 4 + r;
      float val = acc[r] + hb_;
      if (ln < 8) s_offb[mm * 8 + ln] = f2bf(tanhf(val) * 0.04f);
      else if (ln < 12) s_wl[mm * 4 + (ln - 8)] = val;
    }
  }
  __syncthreads();

  // ---- phase 5b: 4-way softmax of sample weights
  if (tid < KM) {
    int k = tid;
    float l0 = s_wl[k * 4], l1 = s_wl[k * 4 + 1], l2 = s_wl[k * 4 + 2], l3 = s_wl[k * 4 + 3];
    float mx = fmaxf(fmaxf(l0, l1), fmaxf(l2, l3));
    float e0 = expf(l0 - mx), e1 = expf(l1 - mx), e2 = expf(l2 - mx), e3 = expf(l3 - mx);
    float si = 1.f / (e0 + e1 + e2 + e3);
    s_wl[k * 4] = e0 * si; s_wl[k * 4 + 1] = e1 * si;
    s_wl[k * 4 + 2] = e2 * si; s_wl[k * 4 + 3] = e3 * si;
  }
  __syncthreads();

  // ---- phase 6: weighted bilinear gather of raw 96-ch bf16 image -> CTX bf16
  {
    int k = tid >> 3, cg = tid & 7;
    float acc[12];
#pragma unroll
    for (int c = 0; c < 12; ++c) acc[c] = 0.f;
    float coef_ = 0.f;
    if (s_vm[k] > 0.f) {
      float rx = s_ref[k * 2], ry = s_ref[k * 2 + 1];
#pragma unroll
      for (int s = 0; s < 4; ++s) {
        float ox = bf2f(s_offb[k * 8 + s * 2]), oy = bf2f(s_offb[k * 8 + s * 2 + 1]);
        float gx = fminf(fmaxf(rx + ox, -1.2f), 1.2f);
        float gy = fminf(fmaxf(ry + oy, -1.2f), 1.2f);
        float px = (gx + 1.f) * 0.5f * 511.f;
        float py = (gy + 1.f) * 0.5f * 159.f;
        float x0f = floorf(px), y0f = floorf(py);
        float wx1 = px - x0f, wy1 = py - y0f;
        float ws_ = s_wl[k * 4 + s];
        int x0 = (int)x0f, y0 = (int)y0f;
#pragma unroll
        for (int t2 = 0; t2 < 4; ++t2) {
          int xi = x0 + (t2 & 1), yi = y0 + (t2 >> 1);
          if (xi >= 0 && xi <= WF - 1 && yi >= 0 && yi <= HF - 1) {
            float tw = ((t2 & 1) ? wx1 : 1.f - wx1) * ((t2 >> 1) ? wy1 : 1.f - wy1);
            float w2 = ws_ * tw;
            coef_ += w2;
            const u16* pp = imgT + ((size_t)(yi * WF + xi)) * 96 + cg * 12;
            uint2 u0 = *(const uint2*)pp;
            uint2 u1 = *(const uint2*)(pp + 4);
            uint2 u2 = *(const uint2*)(pp + 8);
            acc[0] += w2 * bfl(u0.x); acc[1] += w2 * bfh(u0.x);
            acc[2] += w2 * bfl(u0.y); acc[3] += w2 * bfh(u0.y);
            acc[4] += w2 * bfl(u1.x); acc[5] += w2 * bfh(u1.x);
            acc[6] += w2 * bfl(u1.y); acc[7] += w2 * bfh(u1.y);
            acc[8] += w2 * bfl(u2.x); acc[9] += w2 * bfh(u2.x);
            acc[10] += w2 * bfl(u2.y); acc[11] += w2 * bfh(u2.y);
          }
        }
      }
    }
    u16* cp = CTX + k * 96 + cg * 12;
    u32 o0 = (u32)f2bf(acc[0]) | ((u32)f2bf(acc[1]) << 16);
    u32 o1 = (u32)f2bf(acc[2]) | ((u32)f2bf(acc[3]) << 16);
    u32 o2 = (u32)f2bf(acc[4]) | ((u32)f2bf(acc[5]) << 16);
    u32 o3 = (u32)f2bf(acc[6]) | ((u32)f2bf(acc[7]) << 16);
    u32 o4 = (u32)f2bf(acc[8]) | ((u32)f2bf(acc[9]) << 16);
    u32 o5 = (u32)f2bf(acc[10]) | ((u32)f2bf(acc[11]) << 16);
    *(uint2*)cp = make_uint2(o0, o1);
    *(uint2*)(cp + 4) = make_uint2(o2, o3);
    *(uint2*)(cp + 8) = make_uint2(o4, o5);
    if (cg == 0) s_coef[k] = coef_;
  }
  __syncthreads();

  // ---- phase 7: img1 = relu(vm*(h@Wq+bq) + ctx@Fo + coef*fbo + o_b1) -> A1
  // Merged accumulators; vm==0 handled exactly by the select (ctx/coef zero
  // for invalid slots; reference gives relu(o_b1)).
#pragma unroll
  for (int nt = 0; nt < 2; ++nt) {
    int n = n0g + nt * 16 + ln;
    f32x4 aB[4];
#pragma unroll
    for (int mt = 0; mt < 4; ++mt) aB[mt] = (f32x4)0.f;
    const u16* BF = FoT + (size_t)n * 96 + q * 8;
#pragma unroll
    for (int ks = 0; ks < 3; ++ks) {
      short8 b = *(const short8*)(BF + ks * 32);
#pragma unroll
      for (int mt = 0; mt < 4; ++mt) {
        short8 cf = *(const short8*)(CTX + (ln + 16 * mt) * 96 + ks * 32 + q * 8);
        aB[mt] = __builtin_amdgcn_mfma_f32_16x16x32_bf16(cf, b, aB[mt], 0, 0, 0);
      }
    }
    const u16* BW = WqT + (size_t)n * 256 + q * 8;
#pragma unroll
    for (int ks = 0; ks < 8; ++ks) {
      short8 b = *(const short8*)(BW + ks * 32);
#pragma unroll
      for (int mt = 0; mt < 4; ++mt) {
        short8 af = *aGr(A2, ln + 16 * mt, ks * 4 + q);
        aB[mt] = __builtin_amdgcn_mfma_f32_16x16x32_bf16(af, b, aB[mt], 0, 0, 0);
      }
    }
    float fb = fbov[n], ob = o_b1[n], bq_ = bqv[n];
#pragma unroll
    for (int mt = 0; mt < 4; ++mt)
#pragma unroll
      for (int r = 0; r < 4; ++r) {
        int mm = mt * 16 + q * 4 + r;
        float val = (s_vm[mm] > 0.f) ? (aB[mt][r] + bq_ + s_coef[mm] * fb + ob) : ob;
        A1[aIdx(mm, n)] = f2bf(fmaxf(val, 0.f));
      }
  }
  __syncthreads();

  // ---- phase 8: fused = h + img1 @ o_w2 + o_b2 -> A2 (in place, seq-nt)
#pragma unroll
  for (int nt = 0; nt < 2; ++nt) {
    int n = n0g + nt * 16 + ln;
    f32x4 acc[4];
#pragma unroll
    for (int mt = 0; mt < 4; ++mt) acc[mt] = (f32x4)0.f;
    const u16* B = o_w2T + (size_t)n * 256 + q * 8;
#pragma unroll
    for (int ks = 0; ks < 8; ++ks) {
      short8 b = *(const short8*)(B + ks * 32);
#pragma unroll
      for (int mt = 0; mt < 4; ++mt) {
        short8 af = *aGr(A1, ln + 16 * mt, ks * 4 + q);
        acc[mt] = __builtin_amdgcn_mfma_f32_16x16x32_bf16(af, b, acc[mt], 0, 0, 0);
      }
    }
    float b2 = o_b2[n];
#pragma unroll
    for (int mt = 0; mt < 4; ++mt)
#pragma unroll
      for (int r = 0; r < 4; ++r) {
        int mm = mt * 16 + q * 4 + r;
        int i0 = aIdx(mm, n);
        A2[i0] = f2bf(bf2f(A2[i0]) + acc[mt][r] + b2);
      }
  }
  __syncthreads();

  // ---- phase 9: logits partials (poolf reused)
  {
    int k = tid >> 3, part = tid & 7;
    float a = 0.f;
#pragma unroll
    for (int gi = 0; gi < 4; ++gi) {
      int g = part * 4 + gi;
      uint4 uu = *(const uint4*)aGr(A2, k, g);
      const float4* sw = (const float4*)(score_w + g * 8);
      float4 s0 = sw[0], s1 = sw[1];
      a += bfl(uu.x) * s0.x + bfh(uu.x) * s0.y + bfl(uu.y) * s0.z + bfh(uu.y) * s0.w;
      a += bfl(uu.z) * s1.x + bfh(uu.z) * s1.y + bfl(uu.w) * s1.z + bfh(uu.w) * s1.w;
    }
    poolf[k * 8 + part] = a;
  }
  __syncthreads();
  if (tid < KM) {
    float a = score_b[0];
#pragma unroll
    for (int j = 0; j < 8; ++j) a += poolf[tid * 8 + j];
    s_lg[tid] = a;
  }
  __syncthreads();

  // ---- phase 10: softmax over valid slots (wave 0 shuffle reduction)
  if (wv == 0) {
    int k = lane;
    float lg = (k < m) ? s_lg[k] : -1e30f;
    float mx = lg;
#pragma unroll
    for (int o = 32; o; o >>= 1) mx = fmaxf(mx, __shfl_xor(mx, o));
    float e = (k < m) ? expf(lg - mx) : 0.f;
    float ss = e;
#pragma unroll
    for (int o = 32; o; o >>= 1) ss += __shfl_xor(ss, o);
    s_pw[k] = (m > 0 && k < m) ? e / ss : 0.f;
  }
  __syncthreads();

  // ---- phase 11: pooled output
  if (tid < 256) {
    int d = tid;
    float acc = 0.f;
    for (int k = 0; k < KM; ++k) acc += s_pw[k] * bf2f(A2[aIdx(k, d)]);
    out[(size_t)p * 256 + d] = acc;
  }
}

// ------------------------------------------------------------------- launch
extern "C" void kernel_launch(void* const* d_in, const int* in_sizes, int n_in,
                              void* d_out, int out_size, void* d_ws, size_t ws_size,
                              hipStream_t stream) {
  (void)in_sizes; (void)n_in; (void)out_size; (void)ws_size;
  const float* points  = (const float*)d_in[0];
  const float* boxes   = (const float*)d_in[1];
  const float* img     = (const float*)d_in[2];
  const float* proj    = (const float*)d_in[3];
  const float* pe_w1   = (const float*)d_in[4];
  const float* pe_b1   = (const float*)d_in[5];
  const float* pe_w2   = (const float*)d_in[6];
  const float* pe_b2   = (const float*)d_in[7];
  const float* q_w     = (const float*)d_in[8];
  const float* q_b     = (const float*)d_in[9];
  const float* f_w     = (const float*)d_in[10];
  const float* f_b     = (const float*)d_in[11];
  const float* off_w   = (const float*)d_in[12];
  const float* off_b   = (const float*)d_in[13];
  const float* wt_w    = (const float*)d_in[14];
  const float* wt_b    = (const float*)d_in[15];
  const float* o_w1    = (const float*)d_in[16];
  const float* o_b1    = (const float*)d_in[17];
  const float* o_w2    = (const float*)d_in[18];
  const float* o_b2    = (const float*)d_in[19];
  const float* score_w = (const float*)d_in[20];
  const float* score_b = (const float*)d_in[21];
  float* out = (float*)d_out;

  char* W = (char*)d_ws;
  float* xs    = (float*)(W + 0);        // 50176 f
  float* ysv   = (float*)(W + 200704);
  float* zsv   = (float*)(W + 401408);
  float* bqv   = (float*)(W + 602112);   // 256 f
  float* fbov  = (float*)(W + 603136);   // 256 f
  float* hbv   = (float*)(W + 604160);   // 16 f
  u16* pe_w2T  = (u16*)(W + 604416);     // 65536 u16
  u16* WqT     = (u16*)(W + 735488);
  u16* o_w2T   = (u16*)(W + 866560);
  u16* FoT     = (u16*)(W + 997632);     // 24576 u16
  u16* HWT     = (u16*)(W + 1046784);    // 4096 u16
  u16* pe_w1T  = (u16*)(W + 1054976);    // 8192 u16
  u16* imgT    = (u16*)(W + 1071360);    // 160*512*96 u16 -> ends 16800000
  uint4* TOK   = (uint4*)(W + 16800000); // 512*64 uint4 = 524288 B
  float* VM    = (float*)(W + 17324288); // 512*64 f = 131072 B
  float* REF   = (float*)(W + 17455360); // 512*128 f = 262144 B
  int*   CNTW  = (int*)(W + 17717504);   // 512 int

  k_prep<<<1386, 256, 0, stream>>>(points, img, q_w, q_b, f_w, f_b, o_w1, pe_w1, pe_w2,
                                   o_w2, off_w, wt_w, off_b, wt_b, xs, ysv, zsv,
                                   pe_w2T, WqT, o_w2T, FoT, HWT, pe_w1T, bqv, fbov, hbv, imgT);
  k_sel<<<P_BOX, 512, 0, stream>>>(points, boxes, proj, xs, ysv, zsv,
                                   TOK, VM, REF, CNTW, out);
  k_mlp<<<P_BOX, 512, 0, stream>>>(pe_w1T, pe_b1, pe_b2, o_b1, o_b2, score_w, score_b,
                                   pe_w2T, WqT, o_w2T, FoT, HWT, bqv, fbov, hbv, imgT,
                                   TOK, VM, REF, CNTW, out);
}

// Round 10
// 220.793 us; speedup vs baseline: 1.0852x; 1.0852x over previous
//
#include <hip/hip_runtime.h>
#include <hip/hip_bf16.h>

#define P_BOX 512
#define NP    50000
#define NPAD  50176
#define KM    64
#define NKEY  4096
#define HF    160
#define WF    512

typedef unsigned long long u64;
typedef unsigned short u16;
typedef unsigned int u32;
typedef __attribute__((ext_vector_type(8))) short short8;
typedef __attribute__((ext_vector_type(4))) float f32x4;

__device__ __forceinline__ u16 f2bf(float f) {
  u32 u = __float_as_uint(f);
  u32 r = u + 0x7fffu + ((u >> 16) & 1u);
  return (u16)(r >> 16);
}
__device__ __forceinline__ float bf2f(u16 h) { return __uint_as_float(((u32)h) << 16); }
__device__ __forceinline__ float bfl(u32 u) { return __uint_as_float(u << 16); }
__device__ __forceinline__ float bfh(u32 u) { return __uint_as_float(u & 0xffff0000u); }

// A-buffer: 64 rows x 256 bf16, 16B granules XOR-swizzled by row (g' = g ^ (m&7))
__device__ __forceinline__ int aIdx(int m, int d) {
  return m * 256 + (((d >> 3) ^ (m & 7)) << 3) + (d & 7);
}
__device__ __forceinline__ const short8* aGr(const u16* A, int m, int g) {
  return (const short8*)(A + m * 256 + ((g ^ (m & 7)) << 3));
}

// ================= unified prep kernel: 1386 blocks x 256 threads =================
__launch_bounds__(256)
__global__ void k_prep(const float* __restrict__ pts, const float* __restrict__ img,
                       const float* __restrict__ q_w, const float* __restrict__ q_b,
                       const float* __restrict__ f_w, const float* __restrict__ f_b,
                       const float* __restrict__ o_w1, const float* __restrict__ pe_w1,
                       const float* __restrict__ pe_w2, const float* __restrict__ o_w2,
                       const float* __restrict__ off_w, const float* __restrict__ wt_w,
                       const float* __restrict__ off_b, const float* __restrict__ wt_b,
                       float* __restrict__ xs, float* __restrict__ ys, float* __restrict__ zs,
                       u16* __restrict__ pe_w2T, u16* __restrict__ WqT,
                       u16* __restrict__ o_w2T, u16* __restrict__ FoT,
                       u16* __restrict__ HWT, u16* __restrict__ pe_w1T,
                       float* __restrict__ bq, float* __restrict__ fbo,
                       float* __restrict__ hb, u16* __restrict__ imgT) {
  __shared__ float shbuf[8580];
  const int blk = blockIdx.x;
  const int t = threadIdx.x;

  if (blk < 1280) {
    int w0 = (blk & 7) * 64;
    int h = blk >> 3;
    int c0 = t >> 6, w = t & 63;
    for (int it = 0; it < 24; ++it) {
      int c = it * 4 + c0;
      shbuf[c * 65 + w] = img[(c * HF + h) * WF + w0 + w];
    }
    __syncthreads();
    for (int it = 0; it < 24; ++it) {
      int idx = it * 256 + t;
      int ww = idx / 96, c = idx % 96;
      imgT[((size_t)(h * WF + w0 + ww)) * 96 + c] = f2bf(shbuf[c * 65 + ww]);
    }
  } else if (blk < 1329) {
    int g = blk - 1280;
#pragma unroll
    for (int r = 0; r < 4; ++r) {
      int i = g * 1024 + r * 256 + t;
      if (i < NPAD) {
        if (i < NP) {
          xs[i] = pts[i * 7 + 0];
          ys[i] = pts[i * 7 + 1];
          zs[i] = pts[i * 7 + 2];
        } else {
          xs[i] = 1e9f; ys[i] = 1e9f; zs[i] = 1e9f;
        }
      }
    }
  } else if (blk < 1353) {
    int gg = blk - 1329;
    const bool isWq = gg < 16;
    const int g = isWq ? gg : gg - 16;
    const int n0 = (g & 3) * 64;
    const int x0 = (g >> 2) * 64;
    float* sA = shbuf;
    float* sB = shbuf + 64 * 65;
    float acc[4][4];
#pragma unroll
    for (int r = 0; r < 4; ++r)
#pragma unroll
      for (int c = 0; c < 4; ++c) acc[r][c] = 0.f;
    const int tx = t & 15, ty = t >> 4;
    for (int j0 = 0; j0 < 256; j0 += 64) {
      {
        int nn = t & 63, jb = t >> 6;
#pragma unroll
        for (int r = 0; r < 16; ++r) {
          int jj = jb + r * 4;
          int row = (isWq ? 0 : 256) + j0 + jj;
          sA[jj * 65 + nn] = o_w1[row * 256 + n0 + nn];
        }
      }
      {
        int jj = t & 63, xb = t >> 6;
#pragma unroll
        for (int r = 0; r < 16; ++r) {
          int xx = xb + r * 4;
          float v = 0.f;
          if (isWq) v = q_w[(x0 + xx) * 256 + j0 + jj];
          else if (x0 + xx < 96) v = f_w[(x0 + xx) * 256 + j0 + jj];
          sB[jj * 65 + xx] = v;
        }
      }
      __syncthreads();
#pragma unroll 8
      for (int jj = 0; jj < 64; ++jj) {
        float a[4], b[4];
#pragma unroll
        for (int r = 0; r < 4; ++r) a[r] = sA[jj * 65 + ty * 4 + r];
#pragma unroll
        for (int c = 0; c < 4; ++c) b[c] = sB[jj * 65 + tx * 4 + c];
#pragma unroll
        for (int r = 0; r < 4; ++r)
#pragma unroll
          for (int c = 0; c < 4; ++c) acc[r][c] += a[r] * b[c];
      }
      __syncthreads();
    }
    if (isWq) {
#pragma unroll
      for (int r = 0; r < 4; ++r) {
        ushort4 o;
        o.x = f2bf(acc[r][0]); o.y = f2bf(acc[r][1]);
        o.z = f2bf(acc[r][2]); o.w = f2bf(acc[r][3]);
        *(ushort4*)(WqT + (size_t)(n0 + ty * 4 + r) * 256 + x0 + tx * 4) = o;
      }
    } else if (x0 + tx * 4 < 96) {
#pragma unroll
      for (int r = 0; r < 4; ++r) {
        ushort4 o;
        o.x = f2bf(acc[r][0]); o.y = f2bf(acc[r][1]);
        o.z = f2bf(acc[r][2]); o.w = f2bf(acc[r][3]);
        *(ushort4*)(FoT + (size_t)(n0 + ty * 4 + r) * 96 + x0 + tx * 4) = o;
      }
    }
  } else if (blk < 1385) {
    int g = blk - 1353;
    const float* src = (g < 16) ? pe_w2 : o_w2;
    u16* dst = (g < 16) ? pe_w2T : o_w2T;
    int tile = g & 15;
    int n0 = (tile & 3) * 64, k0 = (tile >> 2) * 64;
    {
      int nn = t & 63, kb = t >> 6;
#pragma unroll
      for (int r = 0; r < 16; ++r) {
        int kk = kb + r * 4;
        shbuf[kk * 65 + nn] = src[(k0 + kk) * 256 + n0 + nn];
      }
    }
    __syncthreads();
    {
      int kk = t & 63, nb = t >> 6;
#pragma unroll
      for (int r = 0; r < 16; ++r) {
        int nn = nb + r * 4;
        dst[(size_t)(n0 + nn) * 256 + k0 + kk] = f2bf(shbuf[kk * 65 + nn]);
      }
    }
  } else {
    int n = t;
    float a1 = 0.f, a2 = 0.f;
    for (int j = 0; j < 256; ++j) {
      a1 += q_b[j] * o_w1[j * 256 + n];
      a2 += f_b[j] * o_w1[(256 + j) * 256 + n];
    }
    bq[n] = a1;
    fbo[n] = a2;
#pragma unroll
    for (int s = 0; s < 16; ++s) {
      float v = (s < 8) ? off_w[n * 8 + s] : ((s < 12) ? wt_w[n * 4 + (s - 8)] : 0.f);
      HWT[s * 256 + n] = f2bf(v);
    }
#pragma unroll
    for (int k = 0; k < 32; ++k)
      pe_w1T[n * 32 + k] = (k < 8) ? f2bf(pe_w1[k * 256 + n]) : (u16)0;
    if (t < 16) hb[t] = (t < 8) ? off_b[t] : ((t < 12) ? wt_b[t - 8] : 0.f);
  }
}

// ================ selection kernel: phases 1-3b, NO MFMA =================
__launch_bounds__(512)
__global__ void k_sel(const float* __restrict__ pts, const float* __restrict__ boxes,
                      const float* __restrict__ proj,
                      const float* __restrict__ xs, const float* __restrict__ ys,
                      const float* __restrict__ zs,
                      uint4* __restrict__ TOK, float* __restrict__ VM,
                      float* __restrict__ REF, int* __restrict__ CNT,
                      float* __restrict__ out) {
  __shared__ u64 keys[NKEY];
  __shared__ u64 keys2[KM];
  __shared__ float s_nl[KM * 3], s_ft[KM * 4];
  __shared__ float s_knn[KM * 32];
  __shared__ int cntp;

  const int p = blockIdx.x;
  const int tid = threadIdx.x;

  const float cx = boxes[p * 7 + 0], cy = boxes[p * 7 + 1], cz = boxes[p * 7 + 2];
  const float dx = boxes[p * 7 + 3], dy = boxes[p * 7 + 4], dz = boxes[p * 7 + 5];
  const float yaw = boxes[p * 7 + 6];
  const float cth = cosf(yaw), sth = sinf(yaw);
  const float hx = dx * 0.5f, hy = dy * 0.5f, hz = dz * 0.5f;
  const float ddx = fmaxf(dx, 1e-3f), ddy = fmaxf(dy, 1e-3f), ddz = fmaxf(dz, 1e-3f);

  if (tid == 0) cntp = 0;
  __syncthreads();

  for (int i = tid * 4; i < NPAD; i += 2048) {
    float4 x4 = *(const float4*)(xs + i);
    float4 y4 = *(const float4*)(ys + i);
    float4 z4 = *(const float4*)(zs + i);
#pragma unroll
    for (int c = 0; c < 4; ++c) {
      float xv = (c == 0) ? x4.x : (c == 1) ? x4.y : (c == 2) ? x4.z : x4.w;
      float yv = (c == 0) ? y4.x : (c == 1) ? y4.y : (c == 2) ? y4.z : y4.w;
      float zv = (c == 0) ? z4.x : (c == 1) ? z4.y : (c == 2) ? z4.z : z4.w;
      float rx0 = xv - cx, ry0 = yv - cy, rz0 = zv - cz;
      float lx = rx0 * cth + ry0 * sth;
      float ly = ry0 * cth - rx0 * sth;
      if (fabsf(lx) <= hx && fabsf(ly) <= hy && fabsf(rz0) <= hz) {
        int pos = atomicAdd(&cntp, 1);
        if (pos < NKEY) {
          float nx = lx / ddx, ny = ly / ddy;
          float pl = sqrtf(nx * nx + ny * ny);
          keys[pos] = (((u64)__float_as_uint(pl)) << 32) | (u32)(i + c);
        }
      }
    }
  }
  __syncthreads();
  const int cnt = cntp;
  const int m = min(cnt, KM);

  if (cnt <= KM) {
    if (tid < cnt) keys2[tid] = keys[tid];
  } else {
    int cc = min(cnt, NKEY);
    if (cc <= 1024) {
      u64 k0v = ~0ull, k1v = ~0ull;
      bool h0 = tid < cc, h1 = tid + 512 < cc;
      if (h0) k0v = keys[tid];
      if (h1) k1v = keys[tid + 512];
      int r0 = 0, r1 = 0;
      for (int i = 0; i < cc; ++i) {
        u64 ki = keys[i];
        r0 += (ki < k0v) ? 1 : 0;
        r1 += (ki < k1v) ? 1 : 0;
      }
      if (h0 && r0 < KM) keys2[r0] = k0v;
      if (h1 && r1 < KM) keys2[r1] = k1v;
    } else {
      int nn = 2048;
      while (nn < cc) nn <<= 1;
      for (int i = cc + tid; i < nn; i += 512) keys[i] = ~0ull;
      __syncthreads();
      for (int k = 2; k <= nn; k <<= 1) {
        for (int j = k >> 1; j > 0; j >>= 1) {
          for (int t = tid; t < nn; t += 512) {
            int ixj = t ^ j;
            if (ixj > t) {
              u64 a = keys[t], b = keys[ixj];
              bool up = ((t & k) == 0);
              if ((a > b) == up) { keys[t] = b; keys[ixj] = a; }
            }
          }
          __syncthreads();
        }
      }
      if (tid < KM) keys2[tid] = keys[tid];
    }
  }
  __syncthreads();

  if (tid < KM) {
    int k = tid;
    float x = 0.f, y = 0.f, z = 0.f, n0 = 0.f, n1 = 0.f, n2 = 0.f;
    float f0 = 0.f, f1 = 0.f, f2 = 0.f, f3 = 0.f;
    if (k < m) {
      u32 pi = (u32)(keys2[k] & 0xffffffffu);
      const float* pp = pts + (size_t)pi * 7;
      x = pp[0]; y = pp[1]; z = pp[2];
      f0 = pp[3]; f1 = pp[4]; f2 = pp[5]; f3 = pp[6];
      float rx0 = x - cx, ry0 = y - cy, rz0 = z - cz;
      float lx = rx0 * cth + ry0 * sth;
      float ly = ry0 * cth - rx0 * sth;
      n0 = lx / ddx; n1 = ly / ddy; n2 = rz0 / ddz - 0.5f;
    }
    s_nl[k * 3 + 0] = n0; s_nl[k * 3 + 1] = n1; s_nl[k * 3 + 2] = n2;
    s_ft[k * 4 + 0] = f0; s_ft[k * 4 + 1] = f1; s_ft[k * 4 + 2] = f2; s_ft[k * 4 + 3] = f3;
    float h0 = proj[0] * x + proj[1] * y + proj[2] * z + proj[3];
    float h1 = proj[4] * x + proj[5] * y + proj[6] * z + proj[7];
    float dep = proj[8] * x + proj[9] * y + proj[10] * z + proj[11];
    float sd = (fabsf(dep) > 1e-3f) ? dep : 1e-3f;
    float rx = 2.f * (h0 / sd) / 1279.f - 1.f;
    float ry = 2.f * (h1 / sd) / 383.f - 1.f;
    bool v = (dep > 0.1f) && (fabsf(rx) <= 1.f) && (fabsf(ry) <= 1.f) && (k < m);
    VM[p * KM + k] = v ? 1.f : 0.f;
    REF[p * KM * 2 + k * 2 + 0] = rx;
    REF[p * KM * 2 + k * 2 + 1] = ry;
  }
  __syncthreads();

  {
    int k = tid & 63, part = tid >> 6;
    float a0 = s_nl[k * 3], a1 = s_nl[k * 3 + 1], a2 = s_nl[k * 3 + 2];
    float b0 = 1e30f, b1 = 1e30f, b2 = 1e30f, b3 = 1e30f;
#pragma unroll
    for (int jj = 0; jj < 8; ++jj) {
      int j = part * 8 + jj;
      if (j < m) {
        float d0 = a0 - s_nl[j * 3], d1 = a1 - s_nl[j * 3 + 1], d2 = a2 - s_nl[j * 3 + 2];
        float dd = sqrtf(d0 * d0 + d1 * d1 + d2 * d2 + 1e-12f);
        if (dd < b3) {
          if (dd < b0)      { b3 = b2; b2 = b1; b1 = b0; b0 = dd; }
          else if (dd < b1) { b3 = b2; b2 = b1; b1 = dd; }
          else if (dd < b2) { b3 = b2; b2 = dd; }
          else              { b3 = dd; }
        }
      }
    }
    float* o = s_knn + k * 32 + part * 4;
    o[0] = b0; o[1] = b1; o[2] = b2; o[3] = b3;
  }
  __syncthreads();

  if (tid < KM) {
    int k = tid;
    float dens = 0.f;
    if (k < m) {
      float b0 = 1e30f, b1 = 1e30f, b2 = 1e30f, b3 = 1e30f;
#pragma unroll
      for (int i = 0; i < 32; ++i) {
        float dd = s_knn[k * 32 + i];
        if (dd < b3) {
          if (dd < b0)      { b3 = b2; b2 = b1; b1 = b0; b0 = dd; }
          else if (dd < b1) { b3 = b2; b2 = b1; b1 = dd; }
          else if (dd < b2) { b3 = b2; b2 = dd; }
          else              { b3 = dd; }
        }
      }
      int mm = min(m, 4);
      float nbs = 0.f;
      if (mm > 1) nbs += b1;
      if (mm > 2) nbs += b2;
      if (mm > 3) nbs += b3;
      dens = expf(-nbs / (float)max(mm - 1, 1));
    }
    u32 w0 = (u32)f2bf(s_nl[k * 3 + 0]) | ((u32)f2bf(s_nl[k * 3 + 1]) << 16);
    u32 w1 = (u32)f2bf(s_nl[k * 3 + 2]) | ((u32)f2bf(s_ft[k * 4 + 0]) << 16);
    u32 w2 = (u32)f2bf(s_ft[k * 4 + 1]) | ((u32)f2bf(s_ft[k * 4 + 2]) << 16);
    u32 w3 = (u32)f2bf(s_ft[k * 4 + 3]) | ((u32)f2bf(dens) << 16);
    TOK[p * KM + k] = make_uint4(w0, w1, w2, w3);
  }
  if (tid == 0) {
    CNT[p] = cnt;
    out[(size_t)P_BOX * 256 + p] = (float)cnt;
  }
}

// ================ MLP kernel: phases 4a-11, MFMA-heavy =================
// R9 localization: spills (43.5 MB WRITE) come from fully-unrolled multi-load
// loops -- phase 6 keeps up to 16 taps x 3 uint2 loads in flight (~96 VGPR of
// load dests), ks-loops keep 8 b-fragments (32 VGPR). Under the fixed 64-arch
// cap these pipelined loads spill. Fix: unroll 1 on the gather loops, unroll 2
// on ks-loops -> peak arch demand ~40 -> no spill; latency hiding via the 16
// resident waves/CU (TLP) instead of per-wave ILP.
__attribute__((amdgpu_flat_work_group_size(512, 512), amdgpu_waves_per_eu(4, 4)))
__global__ void k_mlp(const u16* __restrict__ pe_w1T, const float* __restrict__ pe_b1,
                      const float* __restrict__ pe_b2,
                      const float* __restrict__ o_b1, const float* __restrict__ o_b2,
                      const float* __restrict__ score_w, const float* __restrict__ score_b,
                      const u16* __restrict__ pe_w2T, const u16* __restrict__ WqT,
                      const u16* __restrict__ o_w2T, const u16* __restrict__ FoT,
                      const u16* __restrict__ HWT,
                      const float* __restrict__ bqv, const float* __restrict__ fbov,
                      const float* __restrict__ hbv,
                      const u16* __restrict__ imgT,
                      const uint4* __restrict__ TOK, const float* __restrict__ VM,
                      const float* __restrict__ REF, const int* __restrict__ CNT,
                      float* __restrict__ out) {
  __shared__ __align__(16) char smem[81920];
  u16* A1 = (u16*)smem;
  u16* A2 = (u16*)(smem + 32768);
  u16* CTX = (u16*)(smem + 65536);
  float* poolf = (float*)(smem + 65536);
  u16* s_tokb = (u16*)(poolf + 640);
  float* s_vm = (float*)(smem + 77824);
  float* s_coef = s_vm + 64;
  float* s_wl = s_coef + 64;
  float* s_ref = s_wl + 256;
  float* s_lg = s_ref + 128;
  float* s_pw = s_lg + 64;
  u16* s_offb = (u16*)(s_pw + 64);

  const int p = blockIdx.x;
  const int tid = threadIdx.x;
  const int m = min(CNT[p], KM);

  if (tid < KM) {
    int k = tid;
    uint4 tv = TOK[p * KM + k];
    uint4* tb = (uint4*)(s_tokb + k * 32);
    tb[0] = tv;
    tb[1] = make_uint4(0, 0, 0, 0);
    tb[2] = make_uint4(0, 0, 0, 0);
    tb[3] = make_uint4(0, 0, 0, 0);
    s_vm[k] = VM[p * KM + k];
    s_ref[k * 2 + 0] = REF[p * KM * 2 + k * 2 + 0];
    s_ref[k * 2 + 1] = REF[p * KM * 2 + k * 2 + 1];
  }
  __syncthreads();

  const int wv = tid >> 6, lane = tid & 63, q = lane >> 4, ln = lane & 15;
  const int n0g = wv * 32;

  // ---- phase 4a: h1 = relu(tok @ pe_w1 + pe_b1) -> A1 bf16 (MFMA K=32, seq-nt)
#pragma unroll 1
  for (int nt = 0; nt < 2; ++nt) {
    int n = n0g + nt * 16 + ln;
    f32x4 aH[4];
#pragma unroll
    for (int mt = 0; mt < 4; ++mt) aH[mt] = (f32x4)0.f;
    short8 b = *(const short8*)(pe_w1T + (size_t)n * 32 + q * 8);
#pragma unroll
    for (int mt = 0; mt < 4; ++mt) {
      short8 af = *(const short8*)(s_tokb + (ln + 16 * mt) * 32 + q * 8);
      aH[mt] = __builtin_amdgcn_mfma_f32_16x16x32_bf16(af, b, aH[mt], 0, 0, 0);
    }
    float bias = pe_b1[n];
#pragma unroll
    for (int mt = 0; mt < 4; ++mt)
#pragma unroll
      for (int r = 0; r < 4; ++r)
        A1[aIdx(mt * 16 + q * 4 + r, n)] = f2bf(fmaxf(aH[mt][r] + bias, 0.f));
  }
  __syncthreads();

  // ---- phase 4b: h = h1 @ pe_w2 + pe_b2 -> A2 bf16 (MFMA K=256, seq-nt)
#pragma unroll 1
  for (int nt = 0; nt < 2; ++nt) {
    int n = n0g + nt * 16 + ln;
    f32x4 acc[4];
#pragma unroll
    for (int mt = 0; mt < 4; ++mt) acc[mt] = (f32x4)0.f;
    const u16* B = pe_w2T + (size_t)n * 256 + q * 8;
#pragma unroll 2
    for (int ks = 0; ks < 8; ++ks) {
      short8 b = *(const short8*)(B + ks * 32);
#pragma unroll
      for (int mt = 0; mt < 4; ++mt) {
        short8 af = *aGr(A1, ln + 16 * mt, ks * 4 + q);
        acc[mt] = __builtin_amdgcn_mfma_f32_16x16x32_bf16(af, b, acc[mt], 0, 0, 0);
      }
    }
    float bias = pe_b2[n];
#pragma unroll
    for (int mt = 0; mt < 4; ++mt)
#pragma unroll
      for (int r = 0; r < 4; ++r)
        A2[aIdx(mt * 16 + q * 4 + r, n)] = f2bf(acc[mt][r] + bias);
  }
  __syncthreads();

  // ---- phase 5: off/wt heads via one 16-col MFMA (waves 0..3)
  if (wv < 4) {
    f32x4 acc = (f32x4)0.f;
    const u16* B = HWT + (size_t)ln * 256 + q * 8;
#pragma unroll 2
    for (int ks = 0; ks < 8; ++ks) {
      short8 af = *aGr(A2, ln + 16 * wv, ks * 4 + q);
      short8 b = *(const short8*)(B + ks * 32);
      acc = __builtin_amdgcn_mfma_f32_16x16x32_bf16(af, b, acc, 0, 0, 0);
    }
    float hb_ = hbv[ln];
#pragma unroll
    for (int r = 0; r < 4; ++r) {
      int mm = wv * 16 + q * 4 + r;
      float val = acc[r] + hb_;
      if (ln < 8) s_offb[mm * 8 + ln] = f2bf(tanhf(val) * 0.04f);
      else if (ln < 12) s_wl[mm * 4 + (ln - 8)] = val;
    }
  }
  __syncthreads();

  // ---- phase 5b: 4-way softmax of sample weights
  if (tid < KM) {
    int k = tid;
    float l0 = s_wl[k * 4], l1 = s_wl[k * 4 + 1], l2 = s_wl[k * 4 + 2], l3 = s_wl[k * 4 + 3];
    float mx = fmaxf(fmaxf(l0, l1), fmaxf(l2, l3));
    float e0 = expf(l0 - mx), e1 = expf(l1 - mx), e2 = expf(l2 - mx), e3 = expf(l3 - mx);
    float si = 1.f / (e0 + e1 + e2 + e3);
    s_wl[k * 4] = e0 * si; s_wl[k * 4 + 1] = e1 * si;
    s_wl[k * 4 + 2] = e2 * si; s_wl[k * 4 + 3] = e3 * si;
  }
  __syncthreads();

  // ---- phase 6: weighted bilinear gather (unroll 1: cap in-flight loads)
  {
    int k = tid >> 3, cg = tid & 7;
    float acc[12];
#pragma unroll
    for (int c = 0; c < 12; ++c) acc[c] = 0.f;
    float coef_ = 0.f;
    if (s_vm[k] > 0.f) {
      float rx = s_ref[k * 2], ry = s_ref[k * 2 + 1];
#pragma unroll 1
      for (int s = 0; s < 4; ++s) {
        float ox = bf2f(s_offb[k * 8 + s * 2]), oy = bf2f(s_offb[k * 8 + s * 2 + 1]);
        float gx = fminf(fmaxf(rx + ox, -1.2f), 1.2f);
        float gy = fminf(fmaxf(ry + oy, -1.2f), 1.2f);
        float px = (gx + 1.f) * 0.5f * 511.f;
        float py = (gy + 1.f) * 0.5f * 159.f;
        float x0f = floorf(px), y0f = floorf(py);
        float wx1 = px - x0f, wy1 = py - y0f;
        float ws_ = s_wl[k * 4 + s];
        int x0 = (int)x0f, y0 = (int)y0f;
#pragma unroll 1
        for (int t2 = 0; t2 < 4; ++t2) {
          int xi = x0 + (t2 & 1), yi = y0 + (t2 >> 1);
          if (xi >= 0 && xi <= WF - 1 && yi >= 0 && yi <= HF - 1) {
            float tw = ((t2 & 1) ? wx1 : 1.f - wx1) * ((t2 >> 1) ? wy1 : 1.f - wy1);
            float w2 = ws_ * tw;
            coef_ += w2;
            const u16* pp = imgT + ((size_t)(yi * WF + xi)) * 96 + cg * 12;
            uint2 u0 = *(const uint2*)pp;
            uint2 u1 = *(const uint2*)(pp + 4);
            uint2 u2 = *(const uint2*)(pp + 8);
            acc[0] += w2 * bfl(u0.x); acc[1] += w2 * bfh(u0.x);
            acc[2] += w2 * bfl(u0.y); acc[3] += w2 * bfh(u0.y);
            acc[4] += w2 * bfl(u1.x); acc[5] += w2 * bfh(u1.x);
            acc[6] += w2 * bfl(u1.y); acc[7] += w2 * bfh(u1.y);
            acc[8] += w2 * bfl(u2.x); acc[9] += w2 * bfh(u2.x);
            acc[10] += w2 * bfl(u2.y); acc[11] += w2 * bfh(u2.y);
          }
        }
      }
    }
    u16* cp = CTX + k * 96 + cg * 12;
    u32 o0 = (u32)f2bf(acc[0]) | ((u32)f2bf(acc[1]) << 16);
    u32 o1 = (u32)f2bf(acc[2]) | ((u32)f2bf(acc[3]) << 16);
    u32 o2 = (u32)f2bf(acc[4]) | ((u32)f2bf(acc[5]) << 16);
    u32 o3 = (u32)f2bf(acc[6]) | ((u32)f2bf(acc[7]) << 16);
    u32 o4 = (u32)f2bf(acc[8]) | ((u32)f2bf(acc[9]) << 16);
    u32 o5 = (u32)f2bf(acc[10]) | ((u32)f2bf(acc[11]) << 16);
    *(uint2*)cp = make_uint2(o0, o1);
    *(uint2*)(cp + 4) = make_uint2(o2, o3);
    *(uint2*)(cp + 8) = make_uint2(o4, o5);
    if (cg == 0) s_coef[k] = coef_;
  }
  __syncthreads();

  // ---- phase 7: img1 = relu(vm*(h@Wq+bq) + ctx@Fo + coef*fbo + o_b1) -> A1
#pragma unroll 1
  for (int nt = 0; nt < 2; ++nt) {
    int n = n0g + nt * 16 + ln;
    f32x4 aB[4];
#pragma unroll
    for (int mt = 0; mt < 4; ++mt) aB[mt] = (f32x4)0.f;
    const u16* BF = FoT + (size_t)n * 96 + q * 8;
#pragma unroll 1
    for (int ks = 0; ks < 3; ++ks) {
      short8 b = *(const short8*)(BF + ks * 32);
#pragma unroll
      for (int mt = 0; mt < 4; ++mt) {
        short8 cf = *(const short8*)(CTX + (ln + 16 * mt) * 96 + ks * 32 + q * 8);
        aB[mt] = __builtin_amdgcn_mfma_f32_16x16x32_bf16(cf, b, aB[mt], 0, 0, 0);
      }
    }
    const u16* BW = WqT + (size_t)n * 256 + q * 8;
#pragma unroll 2
    for (int ks = 0; ks < 8; ++ks) {
      short8 b = *(const short8*)(BW + ks * 32);
#pragma unroll
      for (int mt = 0; mt < 4; ++mt) {
        short8 af = *aGr(A2, ln + 16 * mt, ks * 4 + q);
        aB[mt] = __builtin_amdgcn_mfma_f32_16x16x32_bf16(af, b, aB[mt], 0, 0, 0);
      }
    }
    float fb = fbov[n], ob = o_b1[n], bq_ = bqv[n];
#pragma unroll
    for (int mt = 0; mt < 4; ++mt)
#pragma unroll
      for (int r = 0; r < 4; ++r) {
        int mm = mt * 16 + q * 4 + r;
        float val = (s_vm[mm] > 0.f) ? (aB[mt][r] + bq_ + s_coef[mm] * fb + ob) : ob;
        A1[aIdx(mm, n)] = f2bf(fmaxf(val, 0.f));
      }
  }
  __syncthreads();

  // ---- phase 8: fused = h + img1 @ o_w2 + o_b2 -> A2 (in place, seq-nt)
#pragma unroll 1
  for (int nt = 0; nt < 2; ++nt) {
    int n = n0g + nt * 16 + ln;
    f32x4 acc[4];
#pragma unroll
    for (int mt = 0; mt < 4; ++mt) acc[mt] = (f32x4)0.f;
    const u16* B = o_w2T + (size_t)n * 256 + q * 8;
#pragma unroll 2
    for (int ks = 0; ks < 8; ++ks) {
      short8 b = *(const short8*)(B + ks * 32);
#pragma unroll
      for (int mt = 0; mt < 4; ++mt) {
        short8 af = *aGr(A1, ln + 16 * mt, ks * 4 + q);
        acc[mt] = __builtin_amdgcn_mfma_f32_16x16x32_bf16(af, b, acc[mt], 0, 0, 0);
      }
    }
    float b2 = o_b2[n];
#pragma unroll
    for (int mt = 0; mt < 4; ++mt)
#pragma unroll
      for (int r = 0; r < 4; ++r) {
        int mm = mt * 16 + q * 4 + r;
        int i0 = aIdx(mm, n);
        A2[i0] = f2bf(bf2f(A2[i0]) + acc[mt][r] + b2);
      }
  }
  __syncthreads();

  // ---- phase 9: logits partials (poolf reused)
  {
    int k = tid >> 3, part = tid & 7;
    float a = 0.f;
#pragma unroll 1
    for (int gi = 0; gi < 4; ++gi) {
      int g = part * 4 + gi;
      uint4 uu = *(const uint4*)aGr(A2, k, g);
      const float4* sw = (const float4*)(score_w + g * 8);
      float4 s0 = sw[0], s1 = sw[1];
      a += bfl(uu.x) * s0.x + bfh(uu.x) * s0.y + bfl(uu.y) * s0.z + bfh(uu.y) * s0.w;
      a += bfl(uu.z) * s1.x + bfh(uu.z) * s1.y + bfl(uu.w) * s1.z + bfh(uu.w) * s1.w;
    }
    poolf[k * 8 + part] = a;
  }
  __syncthreads();
  if (tid < KM) {
    float a = score_b[0];
#pragma unroll
    for (int j = 0; j < 8; ++j) a += poolf[tid * 8 + j];
    s_lg[tid] = a;
  }
  __syncthreads();

  // ---- phase 10: softmax over valid slots (wave 0 shuffle reduction)
  if (wv == 0) {
    int k = lane;
    float lg = (k < m) ? s_lg[k] : -1e30f;
    float mx = lg;
#pragma unroll
    for (int o = 32; o; o >>= 1) mx = fmaxf(mx, __shfl_xor(mx, o));
    float e = (k < m) ? expf(lg - mx) : 0.f;
    float ss = e;
#pragma unroll
    for (int o = 32; o; o >>= 1) ss += __shfl_xor(ss, o);
    s_pw[k] = (m > 0 && k < m) ? e / ss : 0.f;
  }
  __syncthreads();

  // ---- phase 11: pooled output
  if (tid < 256) {
    int d = tid;
    float acc = 0.f;
    for (int k = 0; k < KM; ++k) acc += s_pw[k] * bf2f(A2[aIdx(k, d)]);
    out[(size_t)p * 256 + d] = acc;
  }
}

// ------------------------------------------------------------------- launch
extern "C" void kernel_launch(void* const* d_in, const int* in_sizes, int n_in,
                              void* d_out, int out_size, void* d_ws, size_t ws_size,
                              hipStream_t stream) {
  (void)in_sizes; (void)n_in; (void)out_size; (void)ws_size;
  const float* points  = (const float*)d_in[0];
  const float* boxes   = (const float*)d_in[1];
  const float* img     = (const float*)d_in[2];
  const float* proj    = (const float*)d_in[3];
  const float* pe_w1   = (const float*)d_in[4];
  const float* pe_b1   = (const float*)d_in[5];
  const float* pe_w2   = (const float*)d_in[6];
  const float* pe_b2   = (const float*)d_in[7];
  const float* q_w     = (const float*)d_in[8];
  const float* q_b     = (const float*)d_in[9];
  const float* f_w     = (const float*)d_in[10];
  const float* f_b     = (const float*)d_in[11];
  const float* off_w   = (const float*)d_in[12];
  const float* off_b   = (const float*)d_in[13];
  const float* wt_w    = (const float*)d_in[14];
  const float* wt_b    = (const float*)d_in[15];
  const float* o_w1    = (const float*)d_in[16];
  const float* o_b1    = (const float*)d_in[17];
  const float* o_w2    = (const float*)d_in[18];
  const float* o_b2    = (const float*)d_in[19];
  const float* score_w = (const float*)d_in[20];
  const float* score_b = (const float*)d_in[21];
  float* out = (float*)d_out;

  char* W = (char*)d_ws;
  float* xs    = (float*)(W + 0);
  float* ysv   = (float*)(W + 200704);
  float* zsv   = (float*)(W + 401408);
  float* bqv   = (float*)(W + 602112);
  float* fbov  = (float*)(W + 603136);
  float* hbv   = (float*)(W + 604160);
  u16* pe_w2T  = (u16*)(W + 604416);
  u16* WqT     = (u16*)(W + 735488);
  u16* o_w2T   = (u16*)(W + 866560);
  u16* FoT     = (u16*)(W + 997632);
  u16* HWT     = (u16*)(W + 1046784);
  u16* pe_w1T  = (u16*)(W + 1054976);
  u16* imgT    = (u16*)(W + 1071360);
  uint4* TOK   = (uint4*)(W + 16800000);
  float* VM    = (float*)(W + 17324288);
  float* REF   = (float*)(W + 17455360);
  int*   CNTW  = (int*)(W + 17717504);

  k_prep<<<1386, 256, 0, stream>>>(points, img, q_w, q_b, f_w, f_b, o_w1, pe_w1, pe_w2,
                                   o_w2, off_w, wt_w, off_b, wt_b, xs, ysv, zsv,
                                   pe_w2T, WqT, o_w2T, FoT, HWT, pe_w1T, bqv, fbov, hbv, imgT);
  k_sel<<<P_BOX, 512, 0, stream>>>(points, boxes, proj, xs, ysv, zsv,
                                   TOK, VM, REF, CNTW, out);
  k_mlp<<<P_BOX, 512, 0, stream>>>(pe_w1T, pe_b1, pe_b2, o_b1, o_b2, score_w, score_b,
                                   pe_w2T, WqT, o_w2T, FoT, HWT, bqv, fbov, hbv, imgT,
                                   TOK, VM, REF, CNTW, out);
}

// Round 11
// 216.929 us; speedup vs baseline: 1.1045x; 1.0178x over previous
//
#include <hip/hip_runtime.h>
#include <hip/hip_bf16.h>

#define P_BOX 512
#define NP    50000
#define NPAD  50176
#define KM    64
#define NKEY  4096
#define HF    160
#define WF    512

typedef unsigned long long u64;
typedef unsigned short u16;
typedef unsigned int u32;
typedef __attribute__((ext_vector_type(8))) short short8;
typedef __attribute__((ext_vector_type(4))) float f32x4;

__device__ __forceinline__ u16 f2bf(float f) {
  u32 u = __float_as_uint(f);
  u32 r = u + 0x7fffu + ((u >> 16) & 1u);
  return (u16)(r >> 16);
}
__device__ __forceinline__ float bf2f(u16 h) { return __uint_as_float(((u32)h) << 16); }
__device__ __forceinline__ float bfl(u32 u) { return __uint_as_float(u << 16); }
__device__ __forceinline__ float bfh(u32 u) { return __uint_as_float(u & 0xffff0000u); }

// A-buffer: 64 rows x 256 bf16, 16B granules XOR-swizzled by row (g' = g ^ (m&7))
__device__ __forceinline__ int aIdx(int m, int d) {
  return m * 256 + (((d >> 3) ^ (m & 7)) << 3) + (d & 7);
}
__device__ __forceinline__ const short8* aGr(const u16* A, int m, int g) {
  return (const short8*)(A + m * 256 + ((g ^ (m & 7)) << 3));
}

// ================= unified prep kernel: 243 blocks x 512 threads =================
// R10 diagnosis: old k_prep ran at 0.72 TB/s (VALU 6.7%, occ 7%) -- image role
// used 24 scalar-float loads (256 B/wave) + 24 u16-element stores (128 B/wave)
// per tiny 64-w tile. Rebuild: one block per image row h (160 blocks), LDS slab
// 96x520 u16, float4 loads (1 KB/wave on 2-KB rows) + uint4 stores into 96-KB
// contiguous output slabs. 243 blocks ~= 1/CU: all roles concurrent.
// blk [0,160):   image row transpose f32 -> bf16 pixel-major
// blk [160,185): points AoS -> SoA (padded)
// blk [185,209): fold GEMM tiles: WqT (16) / FoT (8)
// blk [209,241): bf16 transposes of pe_w2 / o_w2
// blk 241:       bq / fbo / HWT / hb / pe_w1T (t<256, no barriers)
__launch_bounds__(512)
__global__ void k_prep(const float* __restrict__ pts, const float* __restrict__ img,
                       const float* __restrict__ q_w, const float* __restrict__ q_b,
                       const float* __restrict__ f_w, const float* __restrict__ f_b,
                       const float* __restrict__ o_w1, const float* __restrict__ pe_w1,
                       const float* __restrict__ pe_w2, const float* __restrict__ o_w2,
                       const float* __restrict__ off_w, const float* __restrict__ wt_w,
                       const float* __restrict__ off_b, const float* __restrict__ wt_b,
                       float* __restrict__ xs, float* __restrict__ ys, float* __restrict__ zs,
                       u16* __restrict__ pe_w2T, u16* __restrict__ WqT,
                       u16* __restrict__ o_w2T, u16* __restrict__ FoT,
                       u16* __restrict__ HWT, u16* __restrict__ pe_w1T,
                       float* __restrict__ bq, float* __restrict__ fbo,
                       float* __restrict__ hb, u16* __restrict__ imgT) {
  __shared__ __align__(16) char smem[99840];  // img: 96x520 u16; GEMM: 2x 64x65 f32
  const int blk = blockIdx.x;
  const int t = threadIdx.x;

  if (blk < 160) {
    // ---------------- image h-slab transpose f32 -> bf16 ----------------
    const int h = blk;
    u16* tile = (u16*)smem;  // [96][520]
    // load: 96 rows x 128 float4; pack to bf16 in LDS
#pragma unroll 4
    for (int it = 0; it < 24; ++it) {
      int idx = it * 512 + t;
      int c = idx >> 7, w4 = idx & 127;
      float4 v = ((const float4*)(img + ((size_t)(c * HF + h)) * WF))[w4];
      ushort4 o;
      o.x = f2bf(v.x); o.y = f2bf(v.y); o.z = f2bf(v.z); o.w = f2bf(v.w);
      *(ushort4*)(tile + c * 520 + w4 * 4) = o;
    }
    __syncthreads();
    // store: 512 w x 12 uint4 (96 u16 per pixel, contiguous 96-KB slab)
#pragma unroll 2
    for (int it = 0; it < 12; ++it) {
      int idx = it * 512 + t;
      int w = idx / 12, cq = idx % 12;
      const u16* tp = tile + (cq * 8) * 520 + w;
      u32 p0 = (u32)tp[0] | ((u32)tp[520] << 16);
      u32 p1 = (u32)tp[1040] | ((u32)tp[1560] << 16);
      u32 p2 = (u32)tp[2080] | ((u32)tp[2600] << 16);
      u32 p3 = (u32)tp[3120] | ((u32)tp[3640] << 16);
      ((uint4*)(imgT + ((size_t)(h * WF + w)) * 96))[cq] = make_uint4(p0, p1, p2, p3);
    }
  } else if (blk < 185) {
    // ---------------- points AoS -> SoA (padded) ----------------
    int g = blk - 160;
#pragma unroll
    for (int r = 0; r < 4; ++r) {
      int i = g * 2048 + r * 512 + t;
      if (i < NPAD) {
        if (i < NP) {
          xs[i] = pts[i * 7 + 0];
          ys[i] = pts[i * 7 + 1];
          zs[i] = pts[i * 7 + 2];
        } else {
          xs[i] = 1e9f; ys[i] = 1e9f; zs[i] = 1e9f;
        }
      }
    }
  } else if (blk < 209) {
    // ---------------- fold GEMMs (fp32, 64x64 tile, 2x4 acc/thread) ----------------
    int gg = blk - 185;
    const bool isWq = gg < 16;
    const int g = isWq ? gg : gg - 16;
    const int n0 = (g & 3) * 64;
    const int x0 = (g >> 2) * 64;
    float* sA = (float*)smem;            // [64][65]
    float* sB = (float*)smem + 64 * 65;  // [64][65]
    float acc[2][4];
#pragma unroll
    for (int r = 0; r < 2; ++r)
#pragma unroll
      for (int c = 0; c < 4; ++c) acc[r][c] = 0.f;
    const int tx = t & 15, ty = t >> 4;  // ty in [0,32): 2 rows each
    for (int j0 = 0; j0 < 256; j0 += 64) {
      {
        int nn = t & 63, jb = t >> 6;
#pragma unroll
        for (int r = 0; r < 8; ++r) {
          int jj = jb + r * 8;
          int row = (isWq ? 0 : 256) + j0 + jj;
          sA[jj * 65 + nn] = o_w1[row * 256 + n0 + nn];
        }
      }
      {
        int jj = t & 63, xb = t >> 6;
#pragma unroll
        for (int r = 0; r < 8; ++r) {
          int xx = xb + r * 8;
          float v = 0.f;
          if (isWq) v = q_w[(x0 + xx) * 256 + j0 + jj];
          else if (x0 + xx < 96) v = f_w[(x0 + xx) * 256 + j0 + jj];
          sB[jj * 65 + xx] = v;
        }
      }
      __syncthreads();
#pragma unroll 8
      for (int jj = 0; jj < 64; ++jj) {
        float a[2], b[4];
#pragma unroll
        for (int r = 0; r < 2; ++r) a[r] = sA[jj * 65 + ty * 2 + r];
#pragma unroll
        for (int c = 0; c < 4; ++c) b[c] = sB[jj * 65 + tx * 4 + c];
#pragma unroll
        for (int r = 0; r < 2; ++r)
#pragma unroll
          for (int c = 0; c < 4; ++c) acc[r][c] += a[r] * b[c];
      }
      __syncthreads();
    }
    if (isWq) {
#pragma unroll
      for (int r = 0; r < 2; ++r) {
        ushort4 o;
        o.x = f2bf(acc[r][0]); o.y = f2bf(acc[r][1]);
        o.z = f2bf(acc[r][2]); o.w = f2bf(acc[r][3]);
        *(ushort4*)(WqT + (size_t)(n0 + ty * 2 + r) * 256 + x0 + tx * 4) = o;
      }
    } else if (x0 + tx * 4 < 96) {
#pragma unroll
      for (int r = 0; r < 2; ++r) {
        ushort4 o;
        o.x = f2bf(acc[r][0]); o.y = f2bf(acc[r][1]);
        o.z = f2bf(acc[r][2]); o.w = f2bf(acc[r][3]);
        *(ushort4*)(FoT + (size_t)(n0 + ty * 2 + r) * 96 + x0 + tx * 4) = o;
      }
    }
  } else if (blk < 241) {
    // ---------------- bf16 transposes (pe_w2, o_w2), 64x64 tiles ----------------
    int g = blk - 209;
    const float* src = (g < 16) ? pe_w2 : o_w2;
    u16* dst = (g < 16) ? pe_w2T : o_w2T;
    int tile_ = g & 15;
    int n0 = (tile_ & 3) * 64, k0 = (tile_ >> 2) * 64;
    float* shf = (float*)smem;  // [64][65]
    {
      int nn = t & 63, kb = t >> 6;
#pragma unroll
      for (int r = 0; r < 8; ++r) {
        int kk = kb + r * 8;
        shf[kk * 65 + nn] = src[(k0 + kk) * 256 + n0 + nn];
      }
    }
    __syncthreads();
    {
      int kk = t & 63, nb = t >> 6;
#pragma unroll
      for (int r = 0; r < 8; ++r) {
        int nn = nb + r * 8;
        dst[(size_t)(n0 + nn) * 256 + k0 + kk] = f2bf(shf[kk * 65 + nn]);
      }
    }
  } else {
    // ---------------- bq / fbo / HWT / hb / pe_w1T (t < 256, no barriers) ----------------
    if (t < 256) {
      int n = t;
      float a1 = 0.f, a2 = 0.f;
      for (int j = 0; j < 256; ++j) {
        a1 += q_b[j] * o_w1[j * 256 + n];
        a2 += f_b[j] * o_w1[(256 + j) * 256 + n];
      }
      bq[n] = a1;
      fbo[n] = a2;
#pragma unroll
      for (int s = 0; s < 16; ++s) {
        float v = (s < 8) ? off_w[n * 8 + s] : ((s < 12) ? wt_w[n * 4 + (s - 8)] : 0.f);
        HWT[s * 256 + n] = f2bf(v);
      }
#pragma unroll
      for (int k = 0; k < 32; ++k)
        pe_w1T[n * 32 + k] = (k < 8) ? f2bf(pe_w1[k * 256 + n]) : (u16)0;
      if (t < 16) hb[t] = (t < 8) ? off_b[t] : ((t < 12) ? wt_b[t - 8] : 0.f);
    }
  }
}

// ================ selection kernel: phases 1-3b, NO MFMA =================
__launch_bounds__(512)
__global__ void k_sel(const float* __restrict__ pts, const float* __restrict__ boxes,
                      const float* __restrict__ proj,
                      const float* __restrict__ xs, const float* __restrict__ ys,
                      const float* __restrict__ zs,
                      uint4* __restrict__ TOK, float* __restrict__ VM,
                      float* __restrict__ REF, int* __restrict__ CNT,
                      float* __restrict__ out) {
  __shared__ u64 keys[NKEY];
  __shared__ u64 keys2[KM];
  __shared__ float s_nl[KM * 3], s_ft[KM * 4];
  __shared__ float s_knn[KM * 32];
  __shared__ int cntp;

  const int p = blockIdx.x;
  const int tid = threadIdx.x;

  const float cx = boxes[p * 7 + 0], cy = boxes[p * 7 + 1], cz = boxes[p * 7 + 2];
  const float dx = boxes[p * 7 + 3], dy = boxes[p * 7 + 4], dz = boxes[p * 7 + 5];
  const float yaw = boxes[p * 7 + 6];
  const float cth = cosf(yaw), sth = sinf(yaw);
  const float hx = dx * 0.5f, hy = dy * 0.5f, hz = dz * 0.5f;
  const float ddx = fmaxf(dx, 1e-3f), ddy = fmaxf(dy, 1e-3f), ddz = fmaxf(dz, 1e-3f);

  if (tid == 0) cntp = 0;
  __syncthreads();

  for (int i = tid * 4; i < NPAD; i += 2048) {
    float4 x4 = *(const float4*)(xs + i);
    float4 y4 = *(const float4*)(ys + i);
    float4 z4 = *(const float4*)(zs + i);
#pragma unroll
    for (int c = 0; c < 4; ++c) {
      float xv = (c == 0) ? x4.x : (c == 1) ? x4.y : (c == 2) ? x4.z : x4.w;
      float yv = (c == 0) ? y4.x : (c == 1) ? y4.y : (c == 2) ? y4.z : y4.w;
      float zv = (c == 0) ? z4.x : (c == 1) ? z4.y : (c == 2) ? z4.z : z4.w;
      float rx0 = xv - cx, ry0 = yv - cy, rz0 = zv - cz;
      float lx = rx0 * cth + ry0 * sth;
      float ly = ry0 * cth - rx0 * sth;
      if (fabsf(lx) <= hx && fabsf(ly) <= hy && fabsf(rz0) <= hz) {
        int pos = atomicAdd(&cntp, 1);
        if (pos < NKEY) {
          float nx = lx / ddx, ny = ly / ddy;
          float pl = sqrtf(nx * nx + ny * ny);
          keys[pos] = (((u64)__float_as_uint(pl)) << 32) | (u32)(i + c);
        }
      }
    }
  }
  __syncthreads();
  const int cnt = cntp;
  const int m = min(cnt, KM);

  if (cnt <= KM) {
    if (tid < cnt) keys2[tid] = keys[tid];
  } else {
    int cc = min(cnt, NKEY);
    if (cc <= 1024) {
      u64 k0v = ~0ull, k1v = ~0ull;
      bool h0 = tid < cc, h1 = tid + 512 < cc;
      if (h0) k0v = keys[tid];
      if (h1) k1v = keys[tid + 512];
      int r0 = 0, r1 = 0;
      for (int i = 0; i < cc; ++i) {
        u64 ki = keys[i];
        r0 += (ki < k0v) ? 1 : 0;
        r1 += (ki < k1v) ? 1 : 0;
      }
      if (h0 && r0 < KM) keys2[r0] = k0v;
      if (h1 && r1 < KM) keys2[r1] = k1v;
    } else {
      int nn = 2048;
      while (nn < cc) nn <<= 1;
      for (int i = cc + tid; i < nn; i += 512) keys[i] = ~0ull;
      __syncthreads();
      for (int k = 2; k <= nn; k <<= 1) {
        for (int j = k >> 1; j > 0; j >>= 1) {
          for (int t = tid; t < nn; t += 512) {
            int ixj = t ^ j;
            if (ixj > t) {
              u64 a = keys[t], b = keys[ixj];
              bool up = ((t & k) == 0);
              if ((a > b) == up) { keys[t] = b; keys[ixj] = a; }
            }
          }
          __syncthreads();
        }
      }
      if (tid < KM) keys2[tid] = keys[tid];
    }
  }
  __syncthreads();

  if (tid < KM) {
    int k = tid;
    float x = 0.f, y = 0.f, z = 0.f, n0 = 0.f, n1 = 0.f, n2 = 0.f;
    float f0 = 0.f, f1 = 0.f, f2 = 0.f, f3 = 0.f;
    if (k < m) {
      u32 pi = (u32)(keys2[k] & 0xffffffffu);
      const float* pp = pts + (size_t)pi * 7;
      x = pp[0]; y = pp[1]; z = pp[2];
      f0 = pp[3]; f1 = pp[4]; f2 = pp[5]; f3 = pp[6];
      float rx0 = x - cx, ry0 = y - cy, rz0 = z - cz;
      float lx = rx0 * cth + ry0 * sth;
      float ly = ry0 * cth - rx0 * sth;
      n0 = lx / ddx; n1 = ly / ddy; n2 = rz0 / ddz - 0.5f;
    }
    s_nl[k * 3 + 0] = n0; s_nl[k * 3 + 1] = n1; s_nl[k * 3 + 2] = n2;
    s_ft[k * 4 + 0] = f0; s_ft[k * 4 + 1] = f1; s_ft[k * 4 + 2] = f2; s_ft[k * 4 + 3] = f3;
    float h0 = proj[0] * x + proj[1] * y + proj[2] * z + proj[3];
    float h1 = proj[4] * x + proj[5] * y + proj[6] * z + proj[7];
    float dep = proj[8] * x + proj[9] * y + proj[10] * z + proj[11];
    float sd = (fabsf(dep) > 1e-3f) ? dep : 1e-3f;
    float rx = 2.f * (h0 / sd) / 1279.f - 1.f;
    float ry = 2.f * (h1 / sd) / 383.f - 1.f;
    bool v = (dep > 0.1f) && (fabsf(rx) <= 1.f) && (fabsf(ry) <= 1.f) && (k < m);
    VM[p * KM + k] = v ? 1.f : 0.f;
    REF[p * KM * 2 + k * 2 + 0] = rx;
    REF[p * KM * 2 + k * 2 + 1] = ry;
  }
  __syncthreads();

  {
    int k = tid & 63, part = tid >> 6;
    float a0 = s_nl[k * 3], a1 = s_nl[k * 3 + 1], a2 = s_nl[k * 3 + 2];
    float b0 = 1e30f, b1 = 1e30f, b2 = 1e30f, b3 = 1e30f;
#pragma unroll
    for (int jj = 0; jj < 8; ++jj) {
      int j = part * 8 + jj;
      if (j < m) {
        float d0 = a0 - s_nl[j * 3], d1 = a1 - s_nl[j * 3 + 1], d2 = a2 - s_nl[j * 3 + 2];
        float dd = sqrtf(d0 * d0 + d1 * d1 + d2 * d2 + 1e-12f);
        if (dd < b3) {
          if (dd < b0)      { b3 = b2; b2 = b1; b1 = b0; b0 = dd; }
          else if (dd < b1) { b3 = b2; b2 = b1; b1 = dd; }
          else if (dd < b2) { b3 = b2; b2 = dd; }
          else              { b3 = dd; }
        }
      }
    }
    float* o = s_knn + k * 32 + part * 4;
    o[0] = b0; o[1] = b1; o[2] = b2; o[3] = b3;
  }
  __syncthreads();

  if (tid < KM) {
    int k = tid;
    float dens = 0.f;
    if (k < m) {
      float b0 = 1e30f, b1 = 1e30f, b2 = 1e30f, b3 = 1e30f;
#pragma unroll
      for (int i = 0; i < 32; ++i) {
        float dd = s_knn[k * 32 + i];
        if (dd < b3) {
          if (dd < b0)      { b3 = b2; b2 = b1; b1 = b0; b0 = dd; }
          else if (dd < b1) { b3 = b2; b2 = b1; b1 = dd; }
          else if (dd < b2) { b3 = b2; b2 = dd; }
          else              { b3 = dd; }
        }
      }
      int mm = min(m, 4);
      float nbs = 0.f;
      if (mm > 1) nbs += b1;
      if (mm > 2) nbs += b2;
      if (mm > 3) nbs += b3;
      dens = expf(-nbs / (float)max(mm - 1, 1));
    }
    u32 w0 = (u32)f2bf(s_nl[k * 3 + 0]) | ((u32)f2bf(s_nl[k * 3 + 1]) << 16);
    u32 w1 = (u32)f2bf(s_nl[k * 3 + 2]) | ((u32)f2bf(s_ft[k * 4 + 0]) << 16);
    u32 w2 = (u32)f2bf(s_ft[k * 4 + 1]) | ((u32)f2bf(s_ft[k * 4 + 2]) << 16);
    u32 w3 = (u32)f2bf(s_ft[k * 4 + 3]) | ((u32)f2bf(dens) << 16);
    TOK[p * KM + k] = make_uint4(w0, w1, w2, w3);
  }
  if (tid == 0) {
    CNT[p] = cnt;
    out[(size_t)P_BOX * 256 + p] = (float)cnt;
  }
}

// ================ MLP kernel: phases 4a-11, MFMA-heavy (R10: spill-free) ======
__attribute__((amdgpu_flat_work_group_size(512, 512), amdgpu_waves_per_eu(4, 4)))
__global__ void k_mlp(const u16* __restrict__ pe_w1T, const float* __restrict__ pe_b1,
                      const float* __restrict__ pe_b2,
                      const float* __restrict__ o_b1, const float* __restrict__ o_b2,
                      const float* __restrict__ score_w, const float* __restrict__ score_b,
                      const u16* __restrict__ pe_w2T, const u16* __restrict__ WqT,
                      const u16* __restrict__ o_w2T, const u16* __restrict__ FoT,
                      const u16* __restrict__ HWT,
                      const float* __restrict__ bqv, const float* __restrict__ fbov,
                      const float* __restrict__ hbv,
                      const u16* __restrict__ imgT,
                      const uint4* __restrict__ TOK, const float* __restrict__ VM,
                      const float* __restrict__ REF, const int* __restrict__ CNT,
                      float* __restrict__ out) {
  __shared__ __align__(16) char smem[81920];
  u16* A1 = (u16*)smem;
  u16* A2 = (u16*)(smem + 32768);
  u16* CTX = (u16*)(smem + 65536);
  float* poolf = (float*)(smem + 65536);
  u16* s_tokb = (u16*)(poolf + 640);
  float* s_vm = (float*)(smem + 77824);
  float* s_coef = s_vm + 64;
  float* s_wl = s_coef + 64;
  float* s_ref = s_wl + 256;
  float* s_lg = s_ref + 128;
  float* s_pw = s_lg + 64;
  u16* s_offb = (u16*)(s_pw + 64);

  const int p = blockIdx.x;
  const int tid = threadIdx.x;
  const int m = min(CNT[p], KM);

  if (tid < KM) {
    int k = tid;
    uint4 tv = TOK[p * KM + k];
    uint4* tb = (uint4*)(s_tokb + k * 32);
    tb[0] = tv;
    tb[1] = make_uint4(0, 0, 0, 0);
    tb[2] = make_uint4(0, 0, 0, 0);
    tb[3] = make_uint4(0, 0, 0, 0);
    s_vm[k] = VM[p * KM + k];
    s_ref[k * 2 + 0] = REF[p * KM * 2 + k * 2 + 0];
    s_ref[k * 2 + 1] = REF[p * KM * 2 + k * 2 + 1];
  }
  __syncthreads();

  const int wv = tid >> 6, lane = tid & 63, q = lane >> 4, ln = lane & 15;
  const int n0g = wv * 32;

#pragma unroll 1
  for (int nt = 0; nt < 2; ++nt) {
    int n = n0g + nt * 16 + ln;
    f32x4 aH[4];
#pragma unroll
    for (int mt = 0; mt < 4; ++mt) aH[mt] = (f32x4)0.f;
    short8 b = *(const short8*)(pe_w1T + (size_t)n * 32 + q * 8);
#pragma unroll
    for (int mt = 0; mt < 4; ++mt) {
      short8 af = *(const short8*)(s_tokb + (ln + 16 * mt) * 32 + q * 8);
      aH[mt] = __builtin_amdgcn_mfma_f32_16x16x32_bf16(af, b, aH[mt], 0, 0, 0);
    }
    float bias = pe_b1[n];
#pragma unroll
    for (int mt = 0; mt < 4; ++mt)
#pragma unroll
      for (int r = 0; r < 4; ++r)
        A1[aIdx(mt * 16 + q * 4 + r, n)] = f2bf(fmaxf(aH[mt][r] + bias, 0.f));
  }
  __syncthreads();

#pragma unroll 1
  for (int nt = 0; nt < 2; ++nt) {
    int n = n0g + nt * 16 + ln;
    f32x4 acc[4];
#pragma unroll
    for (int mt = 0; mt < 4; ++mt) acc[mt] = (f32x4)0.f;
    const u16* B = pe_w2T + (size_t)n * 256 + q * 8;
#pragma unroll 2
    for (int ks = 0; ks < 8; ++ks) {
      short8 b = *(const short8*)(B + ks * 32);
#pragma unroll
      for (int mt = 0; mt < 4; ++mt) {
        short8 af = *aGr(A1, ln + 16 * mt, ks * 4 + q);
        acc[mt] = __builtin_amdgcn_mfma_f32_16x16x32_bf16(af, b, acc[mt], 0, 0, 0);
      }
    }
    float bias = pe_b2[n];
#pragma unroll
    for (int mt = 0; mt < 4; ++mt)
#pragma unroll
      for (int r = 0; r < 4; ++r)
        A2[aIdx(mt * 16 + q * 4 + r, n)] = f2bf(acc[mt][r] + bias);
  }
  __syncthreads();

  if (wv < 4) {
    f32x4 acc = (f32x4)0.f;
    const u16* B = HWT + (size_t)ln * 256 + q * 8;
#pragma unroll 2
    for (int ks = 0; ks < 8; ++ks) {
      short8 af = *aGr(A2, ln + 16 * wv, ks * 4 + q);
      short8 b = *(const short8*)(B + ks * 32);
      acc = __builtin_amdgcn_mfma_f32_16x16x32_bf16(af, b, acc, 0, 0, 0);
    }
    float hb_ = hbv[ln];
#pragma unroll
    for (int r = 0; r < 4; ++r) {
      int mm = wv * 16 + q * 4 + r;
      float val = acc[r] + hb_;
      if (ln < 8) s_offb[mm * 8 + ln] = f2bf(tanhf(val) * 0.04f);
      else if (ln < 12) s_wl[mm * 4 + (ln - 8)] = val;
    }
  }
  __syncthreads();

  if (tid < KM) {
    int k = tid;
    float l0 = s_wl[k * 4], l1 = s_wl[k * 4 + 1], l2 = s_wl[k * 4 + 2], l3 = s_wl[k * 4 + 3];
    float mx = fmaxf(fmaxf(l0, l1), fmaxf(l2, l3));
    float e0 = expf(l0 - mx), e1 = expf(l1 - mx), e2 = expf(l2 - mx), e3 = expf(l3 - mx);
    float si = 1.f / (e0 + e1 + e2 + e3);
    s_wl[k * 4] = e0 * si; s_wl[k * 4 + 1] = e1 * si;
    s_wl[k * 4 + 2] = e2 * si; s_wl[k * 4 + 3] = e3 * si;
  }
  __syncthreads();

  {
    int k = tid >> 3, cg = tid & 7;
    float acc[12];
#pragma unroll
    for (int c = 0; c < 12; ++c) acc[c] = 0.f;
    float coef_ = 0.f;
    if (s_vm[k] > 0.f) {
      float rx = s_ref[k * 2], ry = s_ref[k * 2 + 1];
#pragma unroll 1
      for (int s = 0; s < 4; ++s) {
        float ox = bf2f(s_offb[k * 8 + s * 2]), oy = bf2f(s_offb[k * 8 + s * 2 + 1]);
        float gx = fminf(fmaxf(rx + ox, -1.2f), 1.2f);
        float gy = fminf(fmaxf(ry + oy, -1.2f), 1.2f);
        float px = (gx + 1.f) * 0.5f * 511.f;
        float py = (gy + 1.f) * 0.5f * 159.f;
        float x0f = floorf(px), y0f = floorf(py);
        float wx1 = px - x0f, wy1 = py - y0f;
        float ws_ = s_wl[k * 4 + s];
        int x0 = (int)x0f, y0 = (int)y0f;
#pragma unroll 1
        for (int t2 = 0; t2 < 4; ++t2) {
          int xi = x0 + (t2 & 1), yi = y0 + (t2 >> 1);
          if (xi >= 0 && xi <= WF - 1 && yi >= 0 && yi <= HF - 1) {
            float tw = ((t2 & 1) ? wx1 : 1.f - wx1) * ((t2 >> 1) ? wy1 : 1.f - wy1);
            float w2 = ws_ * tw;
            coef_ += w2;
            const u16* pp = imgT + ((size_t)(yi * WF + xi)) * 96 + cg * 12;
            uint2 u0 = *(const uint2*)pp;
            uint2 u1 = *(const uint2*)(pp + 4);
            uint2 u2 = *(const uint2*)(pp + 8);
            acc[0] += w2 * bfl(u0.x); acc[1] += w2 * bfh(u0.x);
            acc[2] += w2 * bfl(u0.y); acc[3] += w2 * bfh(u0.y);
            acc[4] += w2 * bfl(u1.x); acc[5] += w2 * bfh(u1.x);
            acc[6] += w2 * bfl(u1.y); acc[7] += w2 * bfh(u1.y);
            acc[8] += w2 * bfl(u2.x); acc[9] += w2 * bfh(u2.x);
            acc[10] += w2 * bfl(u2.y); acc[11] += w2 * bfh(u2.y);
          }
        }
      }
    }
    u16* cp = CTX + k * 96 + cg * 12;
    u32 o0 = (u32)f2bf(acc[0]) | ((u32)f2bf(acc[1]) << 16);
    u32 o1 = (u32)f2bf(acc[2]) | ((u32)f2bf(acc[3]) << 16);
    u32 o2 = (u32)f2bf(acc[4]) | ((u32)f2bf(acc[5]) << 16);
    u32 o3 = (u32)f2bf(acc[6]) | ((u32)f2bf(acc[7]) << 16);
    u32 o4 = (u32)f2bf(acc[8]) | ((u32)f2bf(acc[9]) << 16);
    u32 o5 = (u32)f2bf(acc[10]) | ((u32)f2bf(acc[11]) << 16);
    *(uint2*)cp = make_uint2(o0, o1);
    *(uint2*)(cp + 4) = make_uint2(o2, o3);
    *(uint2*)(cp + 8) = make_uint2(o4, o5);
    if (cg == 0) s_coef[k] = coef_;
  }
  __syncthreads();

#pragma unroll 1
  for (int nt = 0; nt < 2; ++nt) {
    int n = n0g + nt * 16 + ln;
    f32x4 aB[4];
#pragma unroll
    for (int mt = 0; mt < 4; ++mt) aB[mt] = (f32x4)0.f;
    const u16* BF = FoT + (size_t)n * 96 + q * 8;
#pragma unroll 1
    for (int ks = 0; ks < 3; ++ks) {
      short8 b = *(const short8*)(BF + ks * 32);
#pragma unroll
      for (int mt = 0; mt < 4; ++mt) {
        short8 cf = *(const short8*)(CTX + (ln + 16 * mt) * 96 + ks * 32 + q * 8);
        aB[mt] = __builtin_amdgcn_mfma_f32_16x16x32_bf16(cf, b, aB[mt], 0, 0, 0);
      }
    }
    const u16* BW = WqT + (size_t)n * 256 + q * 8;
#pragma unroll 2
    for (int ks = 0; ks < 8; ++ks) {
      short8 b = *(const short8*)(BW + ks * 32);
#pragma unroll
      for (int mt = 0; mt < 4; ++mt) {
        short8 af = *aGr(A2, ln + 16 * mt, ks * 4 + q);
        aB[mt] = __builtin_amdgcn_mfma_f32_16x16x32_bf16(af, b, aB[mt], 0, 0, 0);
      }
    }
    float fb = fbov[n], ob = o_b1[n], bq_ = bqv[n];
#pragma unroll
    for (int mt = 0; mt < 4; ++mt)
#pragma unroll
      for (int r = 0; r < 4; ++r) {
        int mm = mt * 16 + q * 4 + r;
        float val = (s_vm[mm] > 0.f) ? (aB[mt][r] + bq_ + s_coef[mm] * fb + ob) : ob;
        A1[aIdx(mm, n)] = f2bf(fmaxf(val, 0.f));
      }
  }
  __syncthreads();

#pragma unroll 1
  for (int nt = 0; nt < 2; ++nt) {
    int n = n0g + nt * 16 + ln;
    f32x4 acc[4];
#pragma unroll
    for (int mt = 0; mt < 4; ++mt) acc[mt] = (f32x4)0.f;
    const u16* B = o_w2T + (size_t)n * 256 + q * 8;
#pragma unroll 2
    for (int ks = 0; ks < 8; ++ks) {
      short8 b = *(const short8*)(B + ks * 32);
#pragma unroll
      for (int mt = 0; mt < 4; ++mt) {
        short8 af = *aGr(A1, ln + 16 * mt, ks * 4 + q);
        acc[mt] = __builtin_amdgcn_mfma_f32_16x16x32_bf16(af, b, acc[mt], 0, 0, 0);
      }
    }
    float b2 = o_b2[n];
#pragma unroll
    for (int mt = 0; mt < 4; ++mt)
#pragma unroll
      for (int r = 0; r < 4; ++r) {
        int mm = mt * 16 + q * 4 + r;
        int i0 = aIdx(mm, n);
        A2[i0] = f2bf(bf2f(A2[i0]) + acc[mt][r] + b2);
      }
  }
  __syncthreads();

  {
    int k = tid >> 3, part = tid & 7;
    float a = 0.f;
#pragma unroll 1
    for (int gi = 0; gi < 4; ++gi) {
      int g = part * 4 + gi;
      uint4 uu = *(const uint4*)aGr(A2, k, g);
      const float4* sw = (const float4*)(score_w + g * 8);
      float4 s0 = sw[0], s1 = sw[1];
      a += bfl(uu.x) * s0.x + bfh(uu.x) * s0.y + bfl(uu.y) * s0.z + bfh(uu.y) * s0.w;
      a += bfl(uu.z) * s1.x + bfh(uu.z) * s1.y + bfl(uu.w) * s1.z + bfh(uu.w) * s1.w;
    }
    poolf[k * 8 + part] = a;
  }
  __syncthreads();
  if (tid < KM) {
    float a = score_b[0];
#pragma unroll
    for (int j = 0; j < 8; ++j) a += poolf[tid * 8 + j];
    s_lg[tid] = a;
  }
  __syncthreads();

  if (wv == 0) {
    int k = lane;
    float lg = (k < m) ? s_lg[k] : -1e30f;
    float mx = lg;
#pragma unroll
    for (int o = 32; o; o >>= 1) mx = fmaxf(mx, __shfl_xor(mx, o));
    float e = (k < m) ? expf(lg - mx) : 0.f;
    float ss = e;
#pragma unroll
    for (int o = 32; o; o >>= 1) ss += __shfl_xor(ss, o);
    s_pw[k] = (m > 0 && k < m) ? e / ss : 0.f;
  }
  __syncthreads();

  if (tid < 256) {
    int d = tid;
    float acc = 0.f;
    for (int k = 0; k < KM; ++k) acc += s_pw[k] * bf2f(A2[aIdx(k, d)]);
    out[(size_t)p * 256 + d] = acc;
  }
}

// ------------------------------------------------------------------- launch
extern "C" void kernel_launch(void* const* d_in, const int* in_sizes, int n_in,
                              void* d_out, int out_size, void* d_ws, size_t ws_size,
                              hipStream_t stream) {
  (void)in_sizes; (void)n_in; (void)out_size; (void)ws_size;
  const float* points  = (const float*)d_in[0];
  const float* boxes   = (const float*)d_in[1];
  const float* img     = (const float*)d_in[2];
  const float* proj    = (const float*)d_in[3];
  const float* pe_w1   = (const float*)d_in[4];
  const float* pe_b1   = (const float*)d_in[5];
  const float* pe_w2   = (const float*)d_in[6];
  const float* pe_b2   = (const float*)d_in[7];
  const float* q_w     = (const float*)d_in[8];
  const float* q_b     = (const float*)d_in[9];
  const float* f_w     = (const float*)d_in[10];
  const float* f_b     = (const float*)d_in[11];
  const float* off_w   = (const float*)d_in[12];
  const float* off_b   = (const float*)d_in[13];
  const float* wt_w    = (const float*)d_in[14];
  const float* wt_b    = (const float*)d_in[15];
  const float* o_w1    = (const float*)d_in[16];
  const float* o_b1    = (const float*)d_in[17];
  const float* o_w2    = (const float*)d_in[18];
  const float* o_b2    = (const float*)d_in[19];
  const float* score_w = (const float*)d_in[20];
  const float* score_b = (const float*)d_in[21];
  float* out = (float*)d_out;

  char* W = (char*)d_ws;
  float* xs    = (float*)(W + 0);
  float* ysv   = (float*)(W + 200704);
  float* zsv   = (float*)(W + 401408);
  float* bqv   = (float*)(W + 602112);
  float* fbov  = (float*)(W + 603136);
  float* hbv   = (float*)(W + 604160);
  u16* pe_w2T  = (u16*)(W + 604416);
  u16* WqT     = (u16*)(W + 735488);
  u16* o_w2T   = (u16*)(W + 866560);
  u16* FoT     = (u16*)(W + 997632);
  u16* HWT     = (u16*)(W + 1046784);
  u16* pe_w1T  = (u16*)(W + 1054976);
  u16* imgT    = (u16*)(W + 1071360);
  uint4* TOK   = (uint4*)(W + 16800000);
  float* VM    = (float*)(W + 17324288);
  float* REF   = (float*)(W + 17455360);
  int*   CNTW  = (int*)(W + 17717504);

  k_prep<<<243, 512, 0, stream>>>(points, img, q_w, q_b, f_w, f_b, o_w1, pe_w1, pe_w2,
                                  o_w2, off_w, wt_w, off_b, wt_b, xs, ysv, zsv,
                                  pe_w2T, WqT, o_w2T, FoT, HWT, pe_w1T, bqv, fbov, hbv, imgT);
  k_sel<<<P_BOX, 512, 0, stream>>>(points, boxes, proj, xs, ysv, zsv,
                                   TOK, VM, REF, CNTW, out);
  k_mlp<<<P_BOX, 512, 0, stream>>>(pe_w1T, pe_b1, pe_b2, o_b1, o_b2, score_w, score_b,
                                   pe_w2T, WqT, o_w2T, FoT, HWT, bqv, fbov, hbv, imgT,
                                   TOK, VM, REF, CNTW, out);
}